// Round 3
// baseline (537.453 us; speedup 1.0000x reference)
//
#include <hip/hip_runtime.h>
#include <hip/hip_fp16.h>

// ---------------------------------------------------------------------------
// Pipeline: transpose_w, node_h (register-tiled GEMM -> hT[head][node][16]
// fp16, alT/arT [head][node]), bucketed CSR build (1024-row buckets, packed
// int bins), row_gather (wave per (row,head), per-head 3.2MB table L2-resident
// via head = blockIdx&7 XCD pinning, fused normalize).
// ---------------------------------------------------------------------------

#define BK    1024     // rows per bucket
#define BSH   10
#define NBMAX 128      // max buckets (N <= 131072)
#define BCAP  18432    // bin capacity per bucket (mean 16384, >+15 sigma)
#define EPB   16       // edges per thread in bin_edges (4096 per block)

// ---- WT[k*128+c] = W[c*128+k] (once, 16384 elems) -------------------------
__global__ __launch_bounds__(256) void transpose_w(
        const float* __restrict__ W, float* __restrict__ WT) {
    int i = blockIdx.x * 256 + threadIdx.x;
    if (i < 16384) {
        int c = i >> 7, k = i & 127;
        WT[k * 128 + c] = W[i];
    }
}

// ---- h = x @ W^T -> hT fp16 [head][node][16], fused alT/arT ---------------
// 128 nodes x 128 cols per block, 256 threads, 8x8 register tile.
// ws stored with 4-word-segment rotation so b128 reads are 2-way (free).
__global__ __launch_bounds__(256) void node_h(
        const float* __restrict__ x, const float* __restrict__ WT,
        const float* __restrict__ att,
        __half* __restrict__ hT, float* __restrict__ alT,
        float* __restrict__ arT, int n) {
    __shared__ float xs[32][128];   // [k][node]  16 KB
    __shared__ float ws[32][128];   // [k][col] segment-rotated, 16 KB
    const int t  = threadIdx.x;
    const int nb = blockIdx.x * 128;
    const int cg = t & 15;          // col group: cols cg*8..+7
    const int ng = t >> 4;          // node group: nodes ng*8..+7

    float acc[8][8];
#pragma unroll
    for (int i = 0; i < 8; ++i)
#pragma unroll
        for (int j = 0; j < 8; ++j) acc[i][j] = 0.f;

    const int  snode  = t >> 1;          // staging: node 0..127
    const int  skoff  = (t & 1) * 16;    // staging: 16 k's per half-thread
    const int  xnode  = nb + snode;
    const bool xvalid = xnode < n;

    for (int k0 = 0; k0 < 128; k0 += 32) {
        float4 v[4];
        if (xvalid) {
            const float4* xp = (const float4*)&x[(size_t)xnode * 128 + k0 + skoff];
#pragma unroll
            for (int j = 0; j < 4; ++j) v[j] = xp[j];
        } else {
#pragma unroll
            for (int j = 0; j < 4; ++j) v[j] = make_float4(0.f, 0.f, 0.f, 0.f);
        }
        float4 wv4[4];
        const float4* wp = (const float4*)&WT[(size_t)k0 * 128];
#pragma unroll
        for (int j = 0; j < 4; ++j) wv4[j] = wp[t + 256 * j];

        __syncthreads();                 // previous chunk fully consumed
        {
            float tmp[16];
            *(float4*)&tmp[0]  = v[0];
            *(float4*)&tmp[4]  = v[1];
            *(float4*)&tmp[8]  = v[2];
            *(float4*)&tmp[12] = v[3];
#pragma unroll
            for (int j = 0; j < 16; ++j)
                xs[skoff + j][snode] = tmp[j];   // 2-way bank alias: free
        }
#pragma unroll
        for (int j = 0; j < 4; ++j) {
            const int idx  = t + 256 * j;        // k*32 + s4
            const int kk   = idx >> 5;
            const int s4   = idx & 31;
            const int slot = (s4 >> 1) | ((s4 & 1) << 4);  // segment rotate
            ((float4*)ws)[kk * 32 + slot] = wv4[j];
        }
        __syncthreads();

#pragma unroll 4
        for (int k = 0; k < 32; ++k) {
            float xv[8], wv[8];
            *(float4*)&xv[0] = *(const float4*)&xs[k][ng * 8];
            *(float4*)&xv[4] = *(const float4*)&xs[k][ng * 8 + 4];
            // orig words 8cg..8cg+3 -> segment 2cg   -> slot cg    (word 4cg)
            // orig words 8cg+4..+7  -> segment 2cg+1 -> slot 16+cg (word 64+4cg)
            *(float4*)&wv[0] = *(const float4*)&ws[k][cg * 4];
            *(float4*)&wv[4] = *(const float4*)&ws[k][64 + cg * 4];
#pragma unroll
            for (int i = 0; i < 8; ++i)
#pragma unroll
                for (int j = 0; j < 8; ++j)
                    acc[i][j] = fmaf(xv[i], wv[j], acc[i][j]);
        }
    }

    // hT write: head = cg>>1, dims (cg&1)*8..+7 of 16, fp16, 16 B per node
    const int head = cg >> 1;
    const int half = cg & 1;
#pragma unroll
    for (int i = 0; i < 8; ++i) {
        const int node = nb + ng * 8 + i;
        if (node < n) {
            __half2 hp[4];
            hp[0] = __floats2half2_rn(acc[i][0], acc[i][1]);
            hp[1] = __floats2half2_rn(acc[i][2], acc[i][3]);
            hp[2] = __floats2half2_rn(acc[i][4], acc[i][5]);
            hp[3] = __floats2half2_rn(acc[i][6], acc[i][7]);
            *(float4*)&hT[(size_t)head * n * 16 + (size_t)node * 16 + half * 8] =
                *(float4*)hp;
        }
    }

    // alT/arT from fp32 accumulators (alpha precision unchanged)
    const int d0 = half * 8;
    float atl[8], atr[8];
    *(float4*)&atl[0] = *(const float4*)&att[head * 32 + d0];
    *(float4*)&atl[4] = *(const float4*)&att[head * 32 + d0 + 4];
    *(float4*)&atr[0] = *(const float4*)&att[head * 32 + 16 + d0];
    *(float4*)&atr[4] = *(const float4*)&att[head * 32 + 16 + d0 + 4];
#pragma unroll
    for (int i = 0; i < 8; ++i) {
        float pl = 0.f, pr = 0.f;
#pragma unroll
        for (int j = 0; j < 8; ++j) {
            pl = fmaf(acc[i][j], atl[j], pl);
            pr = fmaf(acc[i][j], atr[j], pr);
        }
        pl += __shfl_xor(pl, 1, 64);     // combine d 0..7 with d 8..15
        pr += __shfl_xor(pr, 1, 64);
        const int node = nb + ng * 8 + i;
        if (half == 0 && node < n) {
            alT[(size_t)head * n + node] = pl;
            arT[(size_t)head * n + node] = pr;
        }
    }
}

// ---- bin pass: bucket = row >> 10, packed entry = c | (rlow << 17) --------
__global__ __launch_bounds__(256) void bin_edges(
        const int* __restrict__ ei, int* __restrict__ gcur,
        int* __restrict__ bins, int E, int nb) {
    __shared__ int cnt[NBMAX];
    __shared__ int basep[NBMAX];
    const int t    = threadIdx.x;
    const int base = blockIdx.x * (256 * EPB);
    for (int i = t; i < nb; i += 256) cnt[i] = 0;
    __syncthreads();

    int rr[EPB], off[EPB];
#pragma unroll
    for (int j = 0; j < EPB; ++j) {
        const int e = base + j * 256 + t;
        if (e < E) {
            rr[j]  = ei[e];
            off[j] = atomicAdd(&cnt[rr[j] >> BSH], 1);
        } else rr[j] = -1;
    }
    __syncthreads();
    for (int b = t; b < nb; b += 256) {
        const int c = cnt[b];
        basep[b] = (c > 0) ? atomicAdd(&gcur[b], c) : 0;
    }
    __syncthreads();
#pragma unroll
    for (int j = 0; j < EPB; ++j) {
        if (rr[j] >= 0) {
            const int e  = base + j * 256 + t;
            const int cc = ei[E + e];
            const int b  = rr[j] >> BSH;
            const int p  = basep[b] + off[j];
            if (p < BCAP)
                bins[(size_t)b * BCAP + p] = cc | ((rr[j] & (BK - 1)) << 17);
        }
    }
}

// ---- per-bucket degree count --------------------------------------------
__global__ __launch_bounds__(1024) void bin_deg(
        const int* __restrict__ bins, const int* __restrict__ gcur,
        int* __restrict__ deg, int n) {
    __shared__ int ld[BK];
    const int b = blockIdx.x, t = threadIdx.x;
    ld[t] = 0;
    __syncthreads();
    const int cnt = min(gcur[b], BCAP);
    const int* bp = bins + (size_t)b * BCAP;
    for (int i = t; i < cnt; i += 1024)
        atomicAdd(&ld[((unsigned)bp[i]) >> 17], 1);
    __syncthreads();
    const int node = b * BK + t;
    if (node < n) deg[node] = ld[t];
}

// ---- exclusive scan, 1024 elems/block -------------------------------------
__global__ __launch_bounds__(256) void scan_blocks(
        const int* __restrict__ deg, int* __restrict__ rowstart,
        int* __restrict__ bsum, int n) {
    __shared__ int s[256];
    int t = threadIdx.x;
    int base = blockIdx.x * 1024 + t * 4;
    int v0 = (base + 0 < n) ? deg[base + 0] : 0;
    int v1 = (base + 1 < n) ? deg[base + 1] : 0;
    int v2 = (base + 2 < n) ? deg[base + 2] : 0;
    int v3 = (base + 3 < n) ? deg[base + 3] : 0;
    int sum = v0 + v1 + v2 + v3;
    s[t] = sum;
    __syncthreads();
    for (int off = 1; off < 256; off <<= 1) {
        int tmp = (t >= off) ? s[t - off] : 0;
        __syncthreads();
        s[t] += tmp;
        __syncthreads();
    }
    int excl = s[t] - sum;
    if (base + 0 < n) rowstart[base + 0] = excl;
    if (base + 1 < n) rowstart[base + 1] = excl + v0;
    if (base + 2 < n) rowstart[base + 2] = excl + v0 + v1;
    if (base + 3 < n) rowstart[base + 3] = excl + v0 + v1 + v2;
    if (t == 255) bsum[blockIdx.x] = s[255];
}

__global__ __launch_bounds__(256) void scan_top(int* __restrict__ bsum, int nb) {
    __shared__ int s[256];
    int t = threadIdx.x;
    int v = (t < nb) ? bsum[t] : 0;
    s[t] = v;
    __syncthreads();
    for (int off = 1; off < 256; off <<= 1) {
        int tmp = (t >= off) ? s[t - off] : 0;
        __syncthreads();
        s[t] += tmp;
        __syncthreads();
    }
    if (t < nb) bsum[t] = s[t] - v;               // exclusive
}

__global__ __launch_bounds__(256) void scan_add(
        int* __restrict__ rowstart, int* __restrict__ rowend,
        const int* __restrict__ bsum, const int* __restrict__ deg, int n) {
    int i = blockIdx.x * 256 + threadIdx.x;
    if (i < n) {
        int v = rowstart[i] + bsum[i >> 10];
        rowstart[i] = v;
        rowend[i]   = v + deg[i];
    }
}

// ---- per-bucket csr fill: LDS cursors, scatter within ~64 KB window -------
__global__ __launch_bounds__(1024) void csr_fill(
        const int* __restrict__ bins, const int* __restrict__ gcur,
        const int* __restrict__ rowstart, int* __restrict__ csr, int n) {
    __shared__ int cur[BK];
    const int b = blockIdx.x, t = threadIdx.x;
    const int node = b * BK + t;
    cur[t] = (node < n) ? rowstart[node] : 0;
    __syncthreads();
    const int cnt = min(gcur[b], BCAP);
    const int* bp = bins + (size_t)b * BCAP;
    for (int i = t; i < cnt; i += 1024) {
        const int v = bp[i];
        const int q = atomicAdd(&cur[((unsigned)v) >> 17], 1);
        csr[q] = v & 0x1FFFF;
    }
}

// ---- wave per (row, head); head = blockIdx&7 -> XCD-pinned 3.2MB table ----
// 8 edges/iter, 8 lanes/edge (lane sl covers dims 2sl,2sl+1 of head's 16).
__global__ __launch_bounds__(256) void row_gather(
        const int* __restrict__ csr, const int* __restrict__ rowstart,
        const int* __restrict__ rowend,
        const float* __restrict__ pos, const float* __restrict__ alT,
        const float* __restrict__ arT, const __half* __restrict__ hT,
        float* __restrict__ out, int n) {
    const int bi   = blockIdx.x;
    const int g    = bi & 7;                 // head -> XCD (round-robin)
    const int r    = (bi >> 3) * 4 + (threadIdx.x >> 6);
    const int lane = threadIdx.x & 63;
    if (r >= n) return;
    const int sl  = lane & 7;                // dim lane
    const int sub = lane >> 3;               // edge slot
    const int s = rowstart[r];
    const int e = rowend[r];
    if (s >= e) {                            // empty row -> zeros
        if (lane < 8)
            *(float2*)&out[(size_t)r * 128 + g * 16 + sl * 2] =
                make_float2(0.f, 0.f);
        return;
    }
    const __half* hg  = hT + (size_t)g * n * 16;
    const float*  arg = arT + (size_t)g * n;
    const float   alg = alT[(size_t)g * n + r];
    float ax = 0.f, ay = 0.f, rs = 0.f;
    for (int j = s; j < e; j += 8) {
        const int  jj    = j + sub;
        const bool valid = jj < e;
        const int  c     = csr[valid ? jj : s];
        float av = 0.f;
        if (sl == 0 && valid) {
            float a = alg + arg[c];
            a  = (a >= 0.f) ? a : 0.2f * a;
            av = __expf(a) * pos[c];
            rs += av;
        }
        const float alpha = __shfl(av, lane & 56, 64);
        const unsigned hv = *(const unsigned*)(hg + (size_t)c * 16 + sl * 2);
        const float2 f = __half22float2(*(const __half2*)&hv);
        ax = fmaf(alpha, f.x, ax);
        ay = fmaf(alpha, f.y, ay);
    }
    // reduce across the 8 edge slots
    rs += __shfl_xor(rs, 8, 64);
    rs += __shfl_xor(rs, 16, 64);
    rs += __shfl_xor(rs, 32, 64);
    ax += __shfl_xor(ax, 8, 64);
    ax += __shfl_xor(ax, 16, 64);
    ax += __shfl_xor(ax, 32, 64);
    ay += __shfl_xor(ay, 8, 64);
    ay += __shfl_xor(ay, 16, 64);
    ay += __shfl_xor(ay, 32, 64);
    const float rst = __shfl(rs, 0, 64);
    const float sc  = (rst != 0.f) ? (1.f / rst + 1e-16f) : 0.f;
    if (lane < 8)
        *(float2*)&out[(size_t)r * 128 + g * 16 + sl * 2] =
            make_float2(ax * sc, ay * sc);
}

extern "C" void kernel_launch(void* const* d_in, const int* in_sizes, int n_in,
                              void* d_out, int out_size, void* d_ws, size_t ws_size,
                              hipStream_t stream) {
    // identify inputs by unique sizes (robust to ordering)
    const float* x   = nullptr;
    const int*   ei  = nullptr;
    const float* pos = nullptr;
    const float* W   = nullptr;
    const float* att = nullptr;
    int E2 = 0;
    for (int i = 0; i < n_in; ++i) {
        int s = in_sizes[i];
        if      (s == out_size)        x   = (const float*)d_in[i];
        else if (s == out_size / 128)  pos = (const float*)d_in[i];
        else if (s == 16384)           W   = (const float*)d_in[i];
        else if (s == 256)             att = (const float*)d_in[i];
        else { ei = (const int*)d_in[i]; E2 = s; }
    }
    float* out = (float*)d_out;
    const int N_ = out_size / 128;     // 100000
    const int E_ = E2 / 2;             // 1600000
    const int NB = (N_ + BK - 1) / BK; // 98 buckets

    // workspace
    __half* hT = (__half*)d_ws;                       // N*128 halves (25.6 MB)
    float* alT = (float*)(hT + (size_t)N_ * 128);
    float* arT = alT + (size_t)N_ * 8;
    float* WT  = arT + (size_t)N_ * 8;
    int* deg      = (int*)(WT + 16384);
    int* rowstart = deg + N_;
    int* rowend   = rowstart + N_;
    int* bsum     = rowend + N_;
    int* gcur     = bsum + 256;
    int* csr      = gcur + NBMAX;
    int* bins     = csr + E_;                         // NB*BCAP ints (7.2 MB)

    const int nb_scan = (N_ + 1023) / 1024;           // 98 <= 256

    hipMemsetAsync(gcur, 0, (size_t)NBMAX * sizeof(int), stream);

    transpose_w<<<64, 256, 0, stream>>>(W, WT);
    node_h<<<(N_ + 127) / 128, 256, 0, stream>>>(x, WT, att, hT, alT, arT, N_);
    bin_edges<<<(E_ + 256 * EPB - 1) / (256 * EPB), 256, 0, stream>>>(
        ei, gcur, bins, E_, NB);
    bin_deg<<<NB, 1024, 0, stream>>>(bins, gcur, deg, N_);
    scan_blocks<<<nb_scan, 256, 0, stream>>>(deg, rowstart, bsum, N_);
    scan_top<<<1, 256, 0, stream>>>(bsum, nb_scan);
    scan_add<<<(N_ + 255) / 256, 256, 0, stream>>>(rowstart, rowend, bsum, deg, N_);
    csr_fill<<<NB, 1024, 0, stream>>>(bins, gcur, rowstart, csr, N_);
    row_gather<<<((N_ + 3) / 4) * 8, 256, 0, stream>>>(
        csr, rowstart, rowend, pos, alT, arT, hT, out, N_);
}

// Round 4
// 412.606 us; speedup vs baseline: 1.3026x; 1.3026x over previous
//
#include <hip/hip_runtime.h>
#include <hip/hip_fp16.h>

// ---------------------------------------------------------------------------
// Pipeline: transpose_w, node_h (register-tiled GEMM -> hT[head][node][16]
// fp16, alT/arT [head][node]), bucketed CSR build (1024-row buckets, packed
// int bins), row_gather (QUARTER-WAVE per (row,head): 8 edges/iter,
// 2 lanes/edge x 16B loads, no alpha shuffle; head = blockIdx&7 pins each
// 3.2MB per-head table to one XCD's L2).
// ---------------------------------------------------------------------------

#define BK    1024     // rows per bucket
#define BSH   10
#define NBMAX 128      // max buckets (N <= 131072)
#define BCAP  18432    // bin capacity per bucket (mean 16384, >+15 sigma)
#define EPB   16       // edges per thread in bin_edges (4096 per block)

// ---- WT[k*128+c] = W[c*128+k] (once, 16384 elems) -------------------------
__global__ __launch_bounds__(256) void transpose_w(
        const float* __restrict__ W, float* __restrict__ WT) {
    int i = blockIdx.x * 256 + threadIdx.x;
    if (i < 16384) {
        int c = i >> 7, k = i & 127;
        WT[k * 128 + c] = W[i];
    }
}

// ---- h = x @ W^T -> hT fp16 [head][node][16], fused alT/arT ---------------
// 128 nodes x 128 cols per block, 256 threads, 8x8 register tile.
// ws stored with 4-word-segment rotation so b128 reads are 2-way (free).
__global__ __launch_bounds__(256) void node_h(
        const float* __restrict__ x, const float* __restrict__ WT,
        const float* __restrict__ att,
        __half* __restrict__ hT, float* __restrict__ alT,
        float* __restrict__ arT, int n) {
    __shared__ float xs[32][128];   // [k][node]  16 KB
    __shared__ float ws[32][128];   // [k][col] segment-rotated, 16 KB
    const int t  = threadIdx.x;
    const int nb = blockIdx.x * 128;
    const int cg = t & 15;          // col group: cols cg*8..+7
    const int ng = t >> 4;          // node group: nodes ng*8..+7

    float acc[8][8];
#pragma unroll
    for (int i = 0; i < 8; ++i)
#pragma unroll
        for (int j = 0; j < 8; ++j) acc[i][j] = 0.f;

    const int  snode  = t >> 1;          // staging: node 0..127
    const int  skoff  = (t & 1) * 16;    // staging: 16 k's per half-thread
    const int  xnode  = nb + snode;
    const bool xvalid = xnode < n;

    for (int k0 = 0; k0 < 128; k0 += 32) {
        float4 v[4];
        if (xvalid) {
            const float4* xp = (const float4*)&x[(size_t)xnode * 128 + k0 + skoff];
#pragma unroll
            for (int j = 0; j < 4; ++j) v[j] = xp[j];
        } else {
#pragma unroll
            for (int j = 0; j < 4; ++j) v[j] = make_float4(0.f, 0.f, 0.f, 0.f);
        }
        float4 wv4[4];
        const float4* wp = (const float4*)&WT[(size_t)k0 * 128];
#pragma unroll
        for (int j = 0; j < 4; ++j) wv4[j] = wp[t + 256 * j];

        __syncthreads();                 // previous chunk fully consumed
        {
            float tmp[16];
            *(float4*)&tmp[0]  = v[0];
            *(float4*)&tmp[4]  = v[1];
            *(float4*)&tmp[8]  = v[2];
            *(float4*)&tmp[12] = v[3];
#pragma unroll
            for (int j = 0; j < 16; ++j)
                xs[skoff + j][snode] = tmp[j];   // 2-way bank alias: free
        }
#pragma unroll
        for (int j = 0; j < 4; ++j) {
            const int idx  = t + 256 * j;        // k*32 + s4
            const int kk   = idx >> 5;
            const int s4   = idx & 31;
            const int slot = (s4 >> 1) | ((s4 & 1) << 4);  // segment rotate
            ((float4*)ws)[kk * 32 + slot] = wv4[j];
        }
        __syncthreads();

#pragma unroll 4
        for (int k = 0; k < 32; ++k) {
            float xv[8], wv[8];
            *(float4*)&xv[0] = *(const float4*)&xs[k][ng * 8];
            *(float4*)&xv[4] = *(const float4*)&xs[k][ng * 8 + 4];
            // orig words 8cg..8cg+3 -> segment 2cg   -> slot cg    (word 4cg)
            // orig words 8cg+4..+7  -> segment 2cg+1 -> slot 16+cg (word 64+4cg)
            *(float4*)&wv[0] = *(const float4*)&ws[k][cg * 4];
            *(float4*)&wv[4] = *(const float4*)&ws[k][64 + cg * 4];
#pragma unroll
            for (int i = 0; i < 8; ++i)
#pragma unroll
                for (int j = 0; j < 8; ++j)
                    acc[i][j] = fmaf(xv[i], wv[j], acc[i][j]);
        }
    }

    // hT write: head = cg>>1, dims (cg&1)*8..+7 of 16, fp16, 16 B per node
    const int head = cg >> 1;
    const int half = cg & 1;
#pragma unroll
    for (int i = 0; i < 8; ++i) {
        const int node = nb + ng * 8 + i;
        if (node < n) {
            __half2 hp[4];
            hp[0] = __floats2half2_rn(acc[i][0], acc[i][1]);
            hp[1] = __floats2half2_rn(acc[i][2], acc[i][3]);
            hp[2] = __floats2half2_rn(acc[i][4], acc[i][5]);
            hp[3] = __floats2half2_rn(acc[i][6], acc[i][7]);
            *(float4*)&hT[(size_t)head * n * 16 + (size_t)node * 16 + half * 8] =
                *(float4*)hp;
        }
    }

    // alT/arT from fp32 accumulators (alpha precision unchanged)
    const int d0 = half * 8;
    float atl[8], atr[8];
    *(float4*)&atl[0] = *(const float4*)&att[head * 32 + d0];
    *(float4*)&atl[4] = *(const float4*)&att[head * 32 + d0 + 4];
    *(float4*)&atr[0] = *(const float4*)&att[head * 32 + 16 + d0];
    *(float4*)&atr[4] = *(const float4*)&att[head * 32 + 16 + d0 + 4];
#pragma unroll
    for (int i = 0; i < 8; ++i) {
        float pl = 0.f, pr = 0.f;
#pragma unroll
        for (int j = 0; j < 8; ++j) {
            pl = fmaf(acc[i][j], atl[j], pl);
            pr = fmaf(acc[i][j], atr[j], pr);
        }
        pl += __shfl_xor(pl, 1, 64);     // combine d 0..7 with d 8..15
        pr += __shfl_xor(pr, 1, 64);
        const int node = nb + ng * 8 + i;
        if (half == 0 && node < n) {
            alT[(size_t)head * n + node] = pl;
            arT[(size_t)head * n + node] = pr;
        }
    }
}

// ---- bin pass: bucket = row >> 10, packed entry = c | (rlow << 17) --------
__global__ __launch_bounds__(256) void bin_edges(
        const int* __restrict__ ei, int* __restrict__ gcur,
        int* __restrict__ bins, int E, int nb) {
    __shared__ int cnt[NBMAX];
    __shared__ int basep[NBMAX];
    const int t    = threadIdx.x;
    const int base = blockIdx.x * (256 * EPB);
    for (int i = t; i < nb; i += 256) cnt[i] = 0;
    __syncthreads();

    int rr[EPB], off[EPB];
#pragma unroll
    for (int j = 0; j < EPB; ++j) {
        const int e = base + j * 256 + t;
        if (e < E) {
            rr[j]  = ei[e];
            off[j] = atomicAdd(&cnt[rr[j] >> BSH], 1);
        } else rr[j] = -1;
    }
    __syncthreads();
    for (int b = t; b < nb; b += 256) {
        const int c = cnt[b];
        basep[b] = (c > 0) ? atomicAdd(&gcur[b], c) : 0;
    }
    __syncthreads();
#pragma unroll
    for (int j = 0; j < EPB; ++j) {
        if (rr[j] >= 0) {
            const int e  = base + j * 256 + t;
            const int cc = ei[E + e];
            const int b  = rr[j] >> BSH;
            const int p  = basep[b] + off[j];
            if (p < BCAP)
                bins[(size_t)b * BCAP + p] = cc | ((rr[j] & (BK - 1)) << 17);
        }
    }
}

// ---- per-bucket degree count --------------------------------------------
__global__ __launch_bounds__(1024) void bin_deg(
        const int* __restrict__ bins, const int* __restrict__ gcur,
        int* __restrict__ deg, int n) {
    __shared__ int ld[BK];
    const int b = blockIdx.x, t = threadIdx.x;
    ld[t] = 0;
    __syncthreads();
    const int cnt = min(gcur[b], BCAP);
    const int* bp = bins + (size_t)b * BCAP;
    for (int i = t; i < cnt; i += 1024)
        atomicAdd(&ld[((unsigned)bp[i]) >> 17], 1);
    __syncthreads();
    const int node = b * BK + t;
    if (node < n) deg[node] = ld[t];
}

// ---- exclusive scan, 1024 elems/block -------------------------------------
__global__ __launch_bounds__(256) void scan_blocks(
        const int* __restrict__ deg, int* __restrict__ rowstart,
        int* __restrict__ bsum, int n) {
    __shared__ int s[256];
    int t = threadIdx.x;
    int base = blockIdx.x * 1024 + t * 4;
    int v0 = (base + 0 < n) ? deg[base + 0] : 0;
    int v1 = (base + 1 < n) ? deg[base + 1] : 0;
    int v2 = (base + 2 < n) ? deg[base + 2] : 0;
    int v3 = (base + 3 < n) ? deg[base + 3] : 0;
    int sum = v0 + v1 + v2 + v3;
    s[t] = sum;
    __syncthreads();
    for (int off = 1; off < 256; off <<= 1) {
        int tmp = (t >= off) ? s[t - off] : 0;
        __syncthreads();
        s[t] += tmp;
        __syncthreads();
    }
    int excl = s[t] - sum;
    if (base + 0 < n) rowstart[base + 0] = excl;
    if (base + 1 < n) rowstart[base + 1] = excl + v0;
    if (base + 2 < n) rowstart[base + 2] = excl + v0 + v1;
    if (base + 3 < n) rowstart[base + 3] = excl + v0 + v1 + v2;
    if (t == 255) bsum[blockIdx.x] = s[255];
}

__global__ __launch_bounds__(256) void scan_top(int* __restrict__ bsum, int nb) {
    __shared__ int s[256];
    int t = threadIdx.x;
    int v = (t < nb) ? bsum[t] : 0;
    s[t] = v;
    __syncthreads();
    for (int off = 1; off < 256; off <<= 1) {
        int tmp = (t >= off) ? s[t - off] : 0;
        __syncthreads();
        s[t] += tmp;
        __syncthreads();
    }
    if (t < nb) bsum[t] = s[t] - v;               // exclusive
}

__global__ __launch_bounds__(256) void scan_add(
        int* __restrict__ rowstart, int* __restrict__ rowend,
        const int* __restrict__ bsum, const int* __restrict__ deg, int n) {
    int i = blockIdx.x * 256 + threadIdx.x;
    if (i < n) {
        int v = rowstart[i] + bsum[i >> 10];
        rowstart[i] = v;
        rowend[i]   = v + deg[i];
    }
}

// ---- per-bucket csr fill: LDS cursors, scatter within ~64 KB window -------
__global__ __launch_bounds__(1024) void csr_fill(
        const int* __restrict__ bins, const int* __restrict__ gcur,
        const int* __restrict__ rowstart, int* __restrict__ csr, int n) {
    __shared__ int cur[BK];
    const int b = blockIdx.x, t = threadIdx.x;
    const int node = b * BK + t;
    cur[t] = (node < n) ? rowstart[node] : 0;
    __syncthreads();
    const int cnt = min(gcur[b], BCAP);
    const int* bp = bins + (size_t)b * BCAP;
    for (int i = t; i < cnt; i += 1024) {
        const int v = bp[i];
        const int q = atomicAdd(&cur[((unsigned)v) >> 17], 1);
        csr[q] = v & 0x1FFFF;
    }
}

// ---- quarter-wave per (row, head); head = blockIdx&7 -> XCD-pinned table --
// 16 lanes per (row,head): 8 edges/iter, 2 lanes/edge, lane loads 16 B
// (8 fp16 dims). Both lanes of a pair compute alpha redundantly (exec-masked
// lanes cost the same issue slots; removes the per-iter ds_bpermute).
__global__ __launch_bounds__(256) void row_gather(
        const int* __restrict__ csr, const int* __restrict__ rowstart,
        const int* __restrict__ rowend,
        const float* __restrict__ pos, const float* __restrict__ alT,
        const float* __restrict__ arT, const __half* __restrict__ hT,
        float* __restrict__ out, int n) {
    const int g  = blockIdx.x & 7;               // head -> XCD (round-robin)
    const int rb = (blockIdx.x >> 3) * 16;       // 16 rows per block
    const int t  = threadIdx.x;
    const int ql = t & 15;                       // lane within quarter-wave
    const int r  = rb + (t >> 4);
    if (r >= n) return;
    const int es = ql >> 1;                      // edge slot 0..7
    const int hs = ql & 1;                       // dim half: hs*8..+7
    const int s = rowstart[r];
    const int e = rowend[r];
    if (s >= e) {                                // empty row -> zeros
        if (ql < 2) {
            float* op = &out[(size_t)r * 128 + g * 16 + ql * 8];
            *(float4*)op       = make_float4(0.f, 0.f, 0.f, 0.f);
            *(float4*)(op + 4) = make_float4(0.f, 0.f, 0.f, 0.f);
        }
        return;
    }
    const __half* hg  = hT + (size_t)g * n * 16;
    const float*  arg = arT + (size_t)g * n;
    const float   alg = alT[(size_t)g * n + r];
    float acc[8];
#pragma unroll
    for (int i = 0; i < 8; ++i) acc[i] = 0.f;
    float rs = 0.f;
    for (int j = s; j < e; j += 8) {
        const int  jj    = j + es;
        const bool valid = jj < e;
        const int  c     = csr[valid ? jj : s];
        float a  = alg + arg[c];
        a        = fmaxf(a, 0.2f * a);           // LeakyReLU
        float av = __expf(a) * pos[c];
        if (!valid) av = 0.f;
        rs += av;                                // both lanes of pair: equal
        const float4 hv = *(const float4*)(hg + (size_t)c * 16 + hs * 8);
        const __half2* hp = (const __half2*)&hv;
        const float2 f0 = __half22float2(hp[0]);
        const float2 f1 = __half22float2(hp[1]);
        const float2 f2 = __half22float2(hp[2]);
        const float2 f3 = __half22float2(hp[3]);
        acc[0] = fmaf(av, f0.x, acc[0]);
        acc[1] = fmaf(av, f0.y, acc[1]);
        acc[2] = fmaf(av, f1.x, acc[2]);
        acc[3] = fmaf(av, f1.y, acc[3]);
        acc[4] = fmaf(av, f2.x, acc[4]);
        acc[5] = fmaf(av, f2.y, acc[5]);
        acc[6] = fmaf(av, f3.x, acc[6]);
        acc[7] = fmaf(av, f3.y, acc[7]);
    }
    // merge the 8 edge slots (parity classes each hold the full rs)
    rs += __shfl_xor(rs, 2, 64);
    rs += __shfl_xor(rs, 4, 64);
    rs += __shfl_xor(rs, 8, 64);
#pragma unroll
    for (int i = 0; i < 8; ++i) {
        acc[i] += __shfl_xor(acc[i], 2, 64);
        acc[i] += __shfl_xor(acc[i], 4, 64);
        acc[i] += __shfl_xor(acc[i], 8, 64);
    }
    const float sc = (rs != 0.f) ? (1.f / rs + 1e-16f) : 0.f;
    if (ql < 2) {       // lane 0: dims 0-7, lane 1: dims 8-15 (one 64B line)
        float* op = &out[(size_t)r * 128 + g * 16 + ql * 8];
        *(float4*)op       = make_float4(acc[0] * sc, acc[1] * sc,
                                         acc[2] * sc, acc[3] * sc);
        *(float4*)(op + 4) = make_float4(acc[4] * sc, acc[5] * sc,
                                         acc[6] * sc, acc[7] * sc);
    }
}

extern "C" void kernel_launch(void* const* d_in, const int* in_sizes, int n_in,
                              void* d_out, int out_size, void* d_ws, size_t ws_size,
                              hipStream_t stream) {
    // identify inputs by unique sizes (robust to ordering)
    const float* x   = nullptr;
    const int*   ei  = nullptr;
    const float* pos = nullptr;
    const float* W   = nullptr;
    const float* att = nullptr;
    int E2 = 0;
    for (int i = 0; i < n_in; ++i) {
        int s = in_sizes[i];
        if      (s == out_size)        x   = (const float*)d_in[i];
        else if (s == out_size / 128)  pos = (const float*)d_in[i];
        else if (s == 16384)           W   = (const float*)d_in[i];
        else if (s == 256)             att = (const float*)d_in[i];
        else { ei = (const int*)d_in[i]; E2 = s; }
    }
    float* out = (float*)d_out;
    const int N_ = out_size / 128;     // 100000
    const int E_ = E2 / 2;             // 1600000
    const int NB = (N_ + BK - 1) / BK; // 98 buckets

    // workspace
    __half* hT = (__half*)d_ws;                       // N*128 halves (25.6 MB)
    float* alT = (float*)(hT + (size_t)N_ * 128);
    float* arT = alT + (size_t)N_ * 8;
    float* WT  = arT + (size_t)N_ * 8;
    int* deg      = (int*)(WT + 16384);
    int* rowstart = deg + N_;
    int* rowend   = rowstart + N_;
    int* bsum     = rowend + N_;
    int* gcur     = bsum + 256;
    int* csr      = gcur + NBMAX;
    int* bins     = csr + E_;                         // NB*BCAP ints (7.2 MB)

    const int nb_scan = (N_ + 1023) / 1024;           // 98 <= 256

    hipMemsetAsync(gcur, 0, (size_t)NBMAX * sizeof(int), stream);

    transpose_w<<<64, 256, 0, stream>>>(W, WT);
    node_h<<<(N_ + 127) / 128, 256, 0, stream>>>(x, WT, att, hT, alT, arT, N_);
    bin_edges<<<(E_ + 256 * EPB - 1) / (256 * EPB), 256, 0, stream>>>(
        ei, gcur, bins, E_, NB);
    bin_deg<<<NB, 1024, 0, stream>>>(bins, gcur, deg, N_);
    scan_blocks<<<nb_scan, 256, 0, stream>>>(deg, rowstart, bsum, N_);
    scan_top<<<1, 256, 0, stream>>>(bsum, nb_scan);
    scan_add<<<(N_ + 255) / 256, 256, 0, stream>>>(rowstart, rowend, bsum, deg, N_);
    csr_fill<<<NB, 1024, 0, stream>>>(bins, gcur, rowstart, csr, N_);
    row_gather<<<((N_ + 15) / 16) * 8, 256, 0, stream>>>(
        csr, rowstart, rowend, pos, alT, arT, hT, out, N_);
}

// Round 5
// 290.925 us; speedup vs baseline: 1.8474x; 1.4183x over previous
//
#include <hip/hip_runtime.h>
#include <hip/hip_fp16.h>

// ---------------------------------------------------------------------------
// Pipeline: prep_w (W -> MFMA-swizzled fp16 hi/lo tables),
// node_h (MFMA 16x16x32_f16 split-fp16 GEMM -> h fp16 [node][128], al, ar),
// bucketed CSR build (bin_edges -> bucket_scan -> scan_top -> csr_fill),
// row_gather (round-2 proven: wave/row, 4 edges/iter, 16 lanes x 16B fp16).
// ---------------------------------------------------------------------------

#define BK    1024     // rows per bucket (== scan chunk)
#define BSH   10
#define NBMAX 128      // max buckets
#define BCAP  18432    // bin capacity per bucket (mean 16384, >+15 sigma)
#define EPB   16       // edges per thread in bin_edges (4096 per block)

typedef _Float16 half8 __attribute__((ext_vector_type(8)));
typedef float    f32x4 __attribute__((ext_vector_type(4)));

// ---- W[col][k] -> MFMA-B-swizzled fp16 hi/lo tables -----------------------
// WB index = ((ks*8 + ct)*64 + lane)*8 + j ; lane = n + 16*kg ;
// element = W[(ct*16+n)*128 + ks*32 + kg*8 + j]
__global__ __launch_bounds__(256) void prep_w(
        const float* __restrict__ W, _Float16* __restrict__ WBh,
        _Float16* __restrict__ WBl) {
    int i = blockIdx.x * 256 + threadIdx.x;
    if (i < 16384) {
        const int j    = i & 7;
        const int lane = (i >> 3) & 63;
        const int ct   = (i >> 9) & 7;
        const int ks   = i >> 12;
        const int nn   = lane & 15;
        const int kg   = lane >> 4;
        const float w  = W[(ct * 16 + nn) * 128 + ks * 32 + kg * 8 + j];
        const _Float16 hi = (_Float16)w;
        WBh[i] = hi;
        WBl[i] = (_Float16)(w - (float)hi);
    }
}

// ---- h = x @ W^T via MFMA (split-fp16, fp32-grade), fused al/ar -----------
// 64 nodes/block, 4 waves; wave computes 16 nodes x 128 cols (8 coltiles).
// A: row m = lane&15, k = kg*8+j (kg = lane>>4). D: col = ct*16 + (lane&15),
// node-in-16 = kg*4 + r  [m89-verified layouts].
__global__ __launch_bounds__(256) void node_h(
        const float* __restrict__ x, const _Float16* __restrict__ WBh,
        const _Float16* __restrict__ WBl, const float* __restrict__ att,
        _Float16* __restrict__ h, float* __restrict__ al,
        float* __restrict__ ar, int n) {
    const int t    = threadIdx.x;
    const int wv   = t >> 6;
    const int lane = t & 63;
    const int m    = lane & 15;
    const int kg   = lane >> 4;
    const int nodeA = blockIdx.x * 64 + wv * 16 + m;
    const bool avalid = nodeA < n;

    f32x4 acc[8];
#pragma unroll
    for (int ct = 0; ct < 8; ++ct) acc[ct] = (f32x4)0.f;

    const half8* bh = (const half8*)WBh;
    const half8* bl = (const half8*)WBl;

#pragma unroll
    for (int ks = 0; ks < 4; ++ks) {
        float xv[8];
        if (avalid) {
            const float4* xp =
                (const float4*)&x[(size_t)nodeA * 128 + ks * 32 + kg * 8];
            *(float4*)&xv[0] = xp[0];
            *(float4*)&xv[4] = xp[1];
        } else {
#pragma unroll
            for (int j = 0; j < 8; ++j) xv[j] = 0.f;
        }
        half8 axh, axl;
#pragma unroll
        for (int j = 0; j < 8; ++j) {
            const _Float16 hi = (_Float16)xv[j];
            axh[j] = hi;
            axl[j] = (_Float16)(xv[j] - (float)hi);
        }
#pragma unroll
        for (int ct = 0; ct < 8; ++ct) {
            const half8 bhv = bh[(ks * 8 + ct) * 64 + lane];
            const half8 blv = bl[(ks * 8 + ct) * 64 + lane];
            acc[ct] = __builtin_amdgcn_mfma_f32_16x16x32_f16(axl, bhv, acc[ct], 0, 0, 0);
            acc[ct] = __builtin_amdgcn_mfma_f32_16x16x32_f16(axh, blv, acc[ct], 0, 0, 0);
            acc[ct] = __builtin_amdgcn_mfma_f32_16x16x32_f16(axh, bhv, acc[ct], 0, 0, 0);
        }
    }

    // h write: node = base + kg*4 + r, col = ct*16 + m
    const int nodeD0 = blockIdx.x * 64 + wv * 16 + kg * 4;
#pragma unroll
    for (int r = 0; r < 4; ++r) {
        const int node = nodeD0 + r;
        if (node < n) {
#pragma unroll
            for (int ct = 0; ct < 8; ++ct)
                h[(size_t)node * 128 + ct * 16 + m] = (_Float16)acc[ct][r];
        }
    }

    // al/ar: head == ct (col = ct*16 + m -> head = ct, d = m)
    float attl[8], attr[8];
#pragma unroll
    for (int ct = 0; ct < 8; ++ct) {
        attl[ct] = att[ct * 32 + m];
        attr[ct] = att[ct * 32 + 16 + m];
    }
#pragma unroll
    for (int r = 0; r < 4; ++r) {
        const int node = nodeD0 + r;
#pragma unroll
        for (int ct = 0; ct < 8; ++ct) {
            float pl = acc[ct][r] * attl[ct];
            float pr = acc[ct][r] * attr[ct];
            pl += __shfl_xor(pl, 1, 64); pl += __shfl_xor(pl, 2, 64);
            pl += __shfl_xor(pl, 4, 64); pl += __shfl_xor(pl, 8, 64);
            pr += __shfl_xor(pr, 1, 64); pr += __shfl_xor(pr, 2, 64);
            pr += __shfl_xor(pr, 4, 64); pr += __shfl_xor(pr, 8, 64);
            if (m == 0 && node < n) {
                al[node * 8 + ct] = pl;
                ar[node * 8 + ct] = pr;
            }
        }
    }
}

// ---- bin pass: bucket = row >> 10, packed entry = c | (rlow << 17) --------
__global__ __launch_bounds__(256) void bin_edges(
        const int* __restrict__ ei, int* __restrict__ gcur,
        int* __restrict__ bins, int E, int nb) {
    __shared__ int cnt[NBMAX];
    __shared__ int basep[NBMAX];
    const int t    = threadIdx.x;
    const int base = blockIdx.x * (256 * EPB);
    for (int i = t; i < nb; i += 256) cnt[i] = 0;
    __syncthreads();

    int rr[EPB], off[EPB];
#pragma unroll
    for (int j = 0; j < EPB; ++j) {
        const int e = base + j * 256 + t;
        if (e < E) {
            rr[j]  = ei[e];
            off[j] = atomicAdd(&cnt[rr[j] >> BSH], 1);
        } else rr[j] = -1;
    }
    __syncthreads();
    for (int b = t; b < nb; b += 256) {
        const int c = cnt[b];
        basep[b] = (c > 0) ? atomicAdd(&gcur[b], c) : 0;
    }
    __syncthreads();
#pragma unroll
    for (int j = 0; j < EPB; ++j) {
        if (rr[j] >= 0) {
            const int e  = base + j * 256 + t;
            const int cc = ei[E + e];
            const int b  = rr[j] >> BSH;
            const int p  = basep[b] + off[j];
            if (p < BCAP)
                bins[(size_t)b * BCAP + p] = cc | ((rr[j] & (BK - 1)) << 17);
        }
    }
}

// ---- per-bucket degree count + in-bucket exclusive scan (fused) -----------
// bucket size (1024) == scan chunk; writes raw rowstart + bucket total.
__global__ __launch_bounds__(1024) void bucket_scan(
        const int* __restrict__ bins, const int* __restrict__ gcur,
        int* __restrict__ rowstart, int* __restrict__ bsum, int n) {
    __shared__ int ld[BK];
    __shared__ int sc[BK];
    const int b = blockIdx.x, t = threadIdx.x;
    ld[t] = 0;
    __syncthreads();
    const int cnt = min(gcur[b], BCAP);
    const int* bp = bins + (size_t)b * BCAP;
    for (int i = t; i < cnt; i += 1024)
        atomicAdd(&ld[((unsigned)bp[i]) >> 17], 1);
    __syncthreads();
    const int v = ld[t];
    sc[t] = v;
    __syncthreads();
    for (int off = 1; off < 1024; off <<= 1) {
        const int tmp = (t >= off) ? sc[t - off] : 0;
        __syncthreads();
        sc[t] += tmp;
        __syncthreads();
    }
    const int node = b * BK + t;
    if (node < n) rowstart[node] = sc[t] - v;    // exclusive within bucket
    if (t == 1023) bsum[b] = sc[1023];
}

__global__ __launch_bounds__(256) void scan_top(int* __restrict__ bsum, int nb) {
    __shared__ int s[256];
    int t = threadIdx.x;
    int v = (t < nb) ? bsum[t] : 0;
    s[t] = v;
    __syncthreads();
    for (int off = 1; off < 256; off <<= 1) {
        int tmp = (t >= off) ? s[t - off] : 0;
        __syncthreads();
        s[t] += tmp;
        __syncthreads();
    }
    if (t < nb) bsum[t] = s[t] - v;               // exclusive
}

// ---- per-bucket csr fill (fused bsum add + rowstart/rowend finalize) ------
__global__ __launch_bounds__(1024) void csr_fill(
        const int* __restrict__ bins, const int* __restrict__ gcur,
        const int* __restrict__ bsum, int* __restrict__ rowstart,
        int* __restrict__ rowend, int* __restrict__ csr, int n) {
    __shared__ int cur[BK];
    const int b = blockIdx.x, t = threadIdx.x;
    const int node = b * BK + t;
    const int base = bsum[b];
    const int s0 = (node < n) ? rowstart[node] + base : 0;
    cur[t] = s0;
    __syncthreads();
    const int cnt = min(gcur[b], BCAP);
    const int* bp = bins + (size_t)b * BCAP;
    for (int i = t; i < cnt; i += 1024) {
        const int v = bp[i];
        const int q = atomicAdd(&cur[((unsigned)v) >> 17], 1);
        csr[q] = v & 0x1FFFF;
    }
    __syncthreads();
    if (node < n) {
        rowstart[node] = s0;      // finalize (raw + bucket base)
        rowend[node]   = cur[t];
    }
}

// ---- wave per row, 4 edges per iteration (fp16 h) — round-2 proven --------
__global__ __launch_bounds__(256) void row_gather(
        const int* __restrict__ csr, const int* __restrict__ rowstart,
        const int* __restrict__ rowend,
        const float* __restrict__ pos, const float* __restrict__ al,
        const float* __restrict__ ar, const _Float16* __restrict__ h,
        float* __restrict__ out, int n) {
    const int r    = (blockIdx.x * 256 + threadIdx.x) >> 6;
    const int lane = threadIdx.x & 63;
    if (r >= n) return;
    const int s = rowstart[r];
    const int e = rowend[r];
    const int sl = lane & 15;
    if (s >= e) {                       // empty row -> zeros
        if (lane < 16) {
            float4 z = make_float4(0.f, 0.f, 0.f, 0.f);
            *(float4*)&out[(size_t)r * 128 + sl * 8]     = z;
            *(float4*)&out[(size_t)r * 128 + sl * 8 + 4] = z;
        }
        return;
    }
    const int   head = sl >> 1;         // head for this lane's 8 cols
    const float al_l = (sl < 8) ? al[r * 8 + sl] : 0.f;
    float acc[8];
#pragma unroll
    for (int i = 0; i < 8; ++i) acc[i] = 0.f;
    float rs = 0.f;
#pragma unroll 2
    for (int j = s; j < e; j += 4) {
        const int  jj    = j + (lane >> 4);
        const bool valid = jj < e;
        const int  c     = csr[valid ? jj : s];
        float av = 0.f;
        if (sl < 8 && valid) {
            float a = al_l + ar[c * 8 + sl];
            a  = (a >= 0.f) ? a : 0.2f * a;
            av = __expf(a) * pos[c];
            rs += av;
        }
        const float alpha = __shfl(av, (lane & 48) + head, 64);
        float4 hv = *(const float4*)&h[(size_t)c * 128 + sl * 8];
        const __half2* hp = (const __half2*)&hv;
        const float2 f0 = __half22float2(hp[0]);
        const float2 f1 = __half22float2(hp[1]);
        const float2 f2 = __half22float2(hp[2]);
        const float2 f3 = __half22float2(hp[3]);
        acc[0] = fmaf(alpha, f0.x, acc[0]);
        acc[1] = fmaf(alpha, f0.y, acc[1]);
        acc[2] = fmaf(alpha, f1.x, acc[2]);
        acc[3] = fmaf(alpha, f1.y, acc[3]);
        acc[4] = fmaf(alpha, f2.x, acc[4]);
        acc[5] = fmaf(alpha, f2.y, acc[5]);
        acc[6] = fmaf(alpha, f3.x, acc[6]);
        acc[7] = fmaf(alpha, f3.y, acc[7]);
    }
    // merge the four 16-lane groups
    rs += __shfl_xor(rs, 16, 64);
    rs += __shfl_xor(rs, 32, 64);
#pragma unroll
    for (int i = 0; i < 8; ++i) {
        acc[i] += __shfl_xor(acc[i], 16, 64);
        acc[i] += __shfl_xor(acc[i], 32, 64);
    }
    const float rsh = __shfl(rs, (lane & 48) + head, 64); // rowsum for head
    const float sc  = (rsh != 0.f) ? (1.f / rsh + 1e-16f) : 0.f;
    if (lane < 16) {
        float4 o0 = make_float4(acc[0] * sc, acc[1] * sc, acc[2] * sc, acc[3] * sc);
        float4 o1 = make_float4(acc[4] * sc, acc[5] * sc, acc[6] * sc, acc[7] * sc);
        *(float4*)&out[(size_t)r * 128 + sl * 8]     = o0;
        *(float4*)&out[(size_t)r * 128 + sl * 8 + 4] = o1;
    }
}

extern "C" void kernel_launch(void* const* d_in, const int* in_sizes, int n_in,
                              void* d_out, int out_size, void* d_ws, size_t ws_size,
                              hipStream_t stream) {
    // identify inputs by unique sizes (robust to ordering)
    const float* x   = nullptr;
    const int*   ei  = nullptr;
    const float* pos = nullptr;
    const float* W   = nullptr;
    const float* att = nullptr;
    int E2 = 0;
    for (int i = 0; i < n_in; ++i) {
        int s = in_sizes[i];
        if      (s == out_size)        x   = (const float*)d_in[i];
        else if (s == out_size / 128)  pos = (const float*)d_in[i];
        else if (s == 16384)           W   = (const float*)d_in[i];
        else if (s == 256)             att = (const float*)d_in[i];
        else { ei = (const int*)d_in[i]; E2 = s; }
    }
    float* out = (float*)d_out;
    const int N_ = out_size / 128;     // 100000
    const int E_ = E2 / 2;             // 1600000
    const int NB = (N_ + BK - 1) / BK; // 98 buckets

    // workspace
    _Float16* h   = (_Float16*)d_ws;                  // N*128 halves (25.6 MB)
    float* al     = (float*)(h + (size_t)N_ * 128);
    float* ar     = al + (size_t)N_ * 8;
    _Float16* WBh = (_Float16*)(ar + (size_t)N_ * 8);
    _Float16* WBl = WBh + 16384;
    int* rowstart = (int*)(WBl + 16384);
    int* rowend   = rowstart + N_;
    int* bsum     = rowend + N_;
    int* gcur     = bsum + 256;
    int* csr      = gcur + NBMAX;
    int* bins     = csr + E_;                         // NB*BCAP ints (7.2 MB)

    hipMemsetAsync(gcur, 0, (size_t)NBMAX * sizeof(int), stream);

    prep_w<<<64, 256, 0, stream>>>(W, WBh, WBl);
    node_h<<<(N_ + 63) / 64, 256, 0, stream>>>(x, WBh, WBl, att, h, al, ar, N_);
    bin_edges<<<(E_ + 256 * EPB - 1) / (256 * EPB), 256, 0, stream>>>(
        ei, gcur, bins, E_, NB);
    bucket_scan<<<NB, 1024, 0, stream>>>(bins, gcur, rowstart, bsum, N_);
    scan_top<<<1, 256, 0, stream>>>(bsum, NB);
    csr_fill<<<NB, 1024, 0, stream>>>(bins, gcur, bsum, rowstart, rowend, csr, N_);
    row_gather<<<(N_ * 64 + 255) / 256, 256, 0, stream>>>(
        csr, rowstart, rowend, pos, al, ar, h, out, N_);
}

// Round 6
// 283.212 us; speedup vs baseline: 1.8977x; 1.0272x over previous
//
#include <hip/hip_runtime.h>
#include <hip/hip_fp16.h>

// ---------------------------------------------------------------------------
// Pipeline: prep_w (W -> MFMA-swizzled fp16 hi/lo tables),
// node_h (MFMA 16x16x32_f16 split-fp16 GEMM -> h fp16, al, arp{ar,pos}),
// bin_edges (LDS counting-sort -> coalesced bucket bins),
// scan_top (bucket bases from gcur), bucket_fill (count+scan+csr, fused),
// row_gather (wave/row, 4 edges/iter, 16 lanes x 16B fp16, arp 1-line alpha).
// ---------------------------------------------------------------------------

#define BK    512      // rows per bucket
#define BSH   9
#define NBMAX 256      // max buckets (N <= 131072)
#define BCAP  9216     // bin capacity per bucket (mean 8185, >+11 sigma)
#define EPB   16       // edges per thread in bin_edges (4096 per block)

typedef _Float16 half8 __attribute__((ext_vector_type(8)));
typedef float    f32x4 __attribute__((ext_vector_type(4)));

// ---- W[col][k] -> MFMA-B-swizzled fp16 hi/lo tables -----------------------
__global__ __launch_bounds__(256) void prep_w(
        const float* __restrict__ W, _Float16* __restrict__ WBh,
        _Float16* __restrict__ WBl) {
    int i = blockIdx.x * 256 + threadIdx.x;
    if (i < 16384) {
        const int j    = i & 7;
        const int lane = (i >> 3) & 63;
        const int ct   = (i >> 9) & 7;
        const int ks   = i >> 12;
        const int nn   = lane & 15;
        const int kg   = lane >> 4;
        const float w  = W[(ct * 16 + nn) * 128 + ks * 32 + kg * 8 + j];
        const _Float16 hi = (_Float16)w;
        WBh[i] = hi;
        WBl[i] = (_Float16)(w - (float)hi);
    }
}

// ---- h = x @ W^T via MFMA (split-fp16, fp32-grade), fused al / arp --------
// 64 nodes/block, 4 waves; wave computes 16 nodes x 128 cols (8 coltiles).
__global__ __launch_bounds__(256) void node_h(
        const float* __restrict__ x, const _Float16* __restrict__ WBh,
        const _Float16* __restrict__ WBl, const float* __restrict__ att,
        const float* __restrict__ pos,
        _Float16* __restrict__ h, float* __restrict__ al,
        float* __restrict__ arp, int n) {
    const int t    = threadIdx.x;
    const int wv   = t >> 6;
    const int lane = t & 63;
    const int m    = lane & 15;
    const int kg   = lane >> 4;
    const int nodeA = blockIdx.x * 64 + wv * 16 + m;
    const bool avalid = nodeA < n;

    f32x4 acc[8];
#pragma unroll
    for (int ct = 0; ct < 8; ++ct) acc[ct] = (f32x4)0.f;

    const half8* bh = (const half8*)WBh;
    const half8* bl = (const half8*)WBl;

#pragma unroll
    for (int ks = 0; ks < 4; ++ks) {
        float xv[8];
        if (avalid) {
            const float4* xp =
                (const float4*)&x[(size_t)nodeA * 128 + ks * 32 + kg * 8];
            *(float4*)&xv[0] = xp[0];
            *(float4*)&xv[4] = xp[1];
        } else {
#pragma unroll
            for (int j = 0; j < 8; ++j) xv[j] = 0.f;
        }
        half8 axh, axl;
#pragma unroll
        for (int j = 0; j < 8; ++j) {
            const _Float16 hi = (_Float16)xv[j];
            axh[j] = hi;
            axl[j] = (_Float16)(xv[j] - (float)hi);
        }
#pragma unroll
        for (int ct = 0; ct < 8; ++ct) {
            const half8 bhv = bh[(ks * 8 + ct) * 64 + lane];
            const half8 blv = bl[(ks * 8 + ct) * 64 + lane];
            acc[ct] = __builtin_amdgcn_mfma_f32_16x16x32_f16(axl, bhv, acc[ct], 0, 0, 0);
            acc[ct] = __builtin_amdgcn_mfma_f32_16x16x32_f16(axh, blv, acc[ct], 0, 0, 0);
            acc[ct] = __builtin_amdgcn_mfma_f32_16x16x32_f16(axh, bhv, acc[ct], 0, 0, 0);
        }
    }

    // h write: node = base + kg*4 + r, col = ct*16 + m
    const int nodeD0 = blockIdx.x * 64 + wv * 16 + kg * 4;
#pragma unroll
    for (int r = 0; r < 4; ++r) {
        const int node = nodeD0 + r;
        if (node < n) {
#pragma unroll
            for (int ct = 0; ct < 8; ++ct)
                h[(size_t)node * 128 + ct * 16 + m] = (_Float16)acc[ct][r];
        }
    }

    // al / arp (ar packed with pos into 64B records) from fp32 accumulators
    float attl[8], attr[8];
#pragma unroll
    for (int ct = 0; ct < 8; ++ct) {
        attl[ct] = att[ct * 32 + m];
        attr[ct] = att[ct * 32 + 16 + m];
    }
#pragma unroll
    for (int r = 0; r < 4; ++r) {
        const int node = nodeD0 + r;
#pragma unroll
        for (int ct = 0; ct < 8; ++ct) {
            float pl = acc[ct][r] * attl[ct];
            float pr = acc[ct][r] * attr[ct];
            pl += __shfl_xor(pl, 1, 64); pl += __shfl_xor(pl, 2, 64);
            pl += __shfl_xor(pl, 4, 64); pl += __shfl_xor(pl, 8, 64);
            pr += __shfl_xor(pr, 1, 64); pr += __shfl_xor(pr, 2, 64);
            pr += __shfl_xor(pr, 4, 64); pr += __shfl_xor(pr, 8, 64);
            if (m == 0 && node < n) {
                al[node * 8 + ct] = pl;
                arp[(size_t)node * 16 + ct] = pr;
            }
        }
        if (m == 0 && node < n)
            arp[(size_t)node * 16 + 8] = pos[node];
    }
}

// ---- bin pass: LDS counting-sort by bucket, coalesced bin writes ----------
// bucket = row >> 9; packed entry = c | (rlow << 17)  (c<2^17, rlow<2^9).
__global__ __launch_bounds__(256) void bin_edges(
        const int* __restrict__ ei, int* __restrict__ gcur,
        int* __restrict__ bins, int E, int nb) {
    __shared__ int  cnt[NBMAX];
    __shared__ int  basep[NBMAX];
    __shared__ int  lstart[NBMAX];
    __shared__ int2 sorted[256 * EPB];        // 32 KB
    const int t    = threadIdx.x;
    const int base = blockIdx.x * (256 * EPB);
    cnt[t] = 0;
    __syncthreads();

    int rr[EPB], off[EPB];
#pragma unroll
    for (int j = 0; j < EPB; ++j) {
        const int e = base + j * 256 + t;
        if (e < E) {
            rr[j]  = ei[e];
            off[j] = atomicAdd(&cnt[rr[j] >> BSH], 1);
        } else rr[j] = -1;
    }
    __syncthreads();
    // exclusive scan of cnt -> lstart; reserve global space -> basep
    const int v = cnt[t];
    lstart[t] = v;
    __syncthreads();
    for (int o = 1; o < 256; o <<= 1) {
        const int tmp = (t >= o) ? lstart[t - o] : 0;
        __syncthreads();
        lstart[t] += tmp;
        __syncthreads();
    }
    const int incl = lstart[t];
    __syncthreads();
    lstart[t] = incl - v;                     // exclusive
    basep[t]  = (t < nb && v > 0) ? atomicAdd(&gcur[t], v) : 0;
    __syncthreads();

    // place into LDS sorted by bucket
#pragma unroll
    for (int j = 0; j < EPB; ++j) {
        if (rr[j] >= 0) {
            const int e = base + j * 256 + t;
            const int b = rr[j] >> BSH;
            sorted[lstart[b] + off[j]] = make_int2(ei[E + e], rr[j]);
        }
    }
    __syncthreads();

    // coalesced write-out (runs per bucket are contiguous)
    const int total = lstart[255] + cnt[255];
    for (int i = t; i < total; i += 256) {
        const int2 p = sorted[i];
        const int  b = p.y >> BSH;
        const int  q = basep[b] + i - lstart[b];
        if (q < BCAP)
            bins[(size_t)b * BCAP + q] = p.x | ((p.y & (BK - 1)) << 17);
    }
}

// ---- bucket bases: exclusive scan of clamped gcur -------------------------
__global__ __launch_bounds__(256) void scan_top(
        const int* __restrict__ gcur, int* __restrict__ bbase, int nb) {
    __shared__ int s[256];
    const int t = threadIdx.x;
    const int v = (t < nb) ? min(gcur[t], BCAP) : 0;
    s[t] = v;
    __syncthreads();
    for (int o = 1; o < 256; o <<= 1) {
        const int tmp = (t >= o) ? s[t - o] : 0;
        __syncthreads();
        s[t] += tmp;
        __syncthreads();
    }
    if (t < nb) bbase[t] = s[t] - v;          // exclusive
}

// ---- fused per-bucket: degree count + scan + csr scatter + rowstart/end ---
// (bins read twice; second read is L2-hot: 36 KB/block)
__global__ __launch_bounds__(512) void bucket_fill(
        const int* __restrict__ bins, const int* __restrict__ gcur,
        const int* __restrict__ bbase, int* __restrict__ rowstart,
        int* __restrict__ rowend, int* __restrict__ csr, int n) {
    __shared__ int ld[BK], sc[BK], cur[BK];
    const int b = blockIdx.x, t = threadIdx.x;
    ld[t] = 0;
    __syncthreads();
    const int cnt = min(gcur[b], BCAP);
    const int* bp = bins + (size_t)b * BCAP;
    for (int i = t; i < cnt; i += 512)
        atomicAdd(&ld[((unsigned)bp[i]) >> 17], 1);
    __syncthreads();
    const int v = ld[t];
    sc[t] = v;
    __syncthreads();
    for (int o = 1; o < 512; o <<= 1) {
        const int tmp = (t >= o) ? sc[t - o] : 0;
        __syncthreads();
        sc[t] += tmp;
        __syncthreads();
    }
    const int node = b * BK + t;
    const int s0   = sc[t] - v + bbase[b];
    cur[t] = s0;
    if (node < n) rowstart[node] = s0;
    __syncthreads();
    for (int i = t; i < cnt; i += 512) {
        const int vv = bp[i];
        const int q  = atomicAdd(&cur[((unsigned)vv) >> 17], 1);
        csr[q] = vv & 0x1FFFF;
    }
    __syncthreads();
    if (node < n) rowend[node] = cur[t];
}

// ---- wave per row, 4 edges per iteration (fp16 h, arp 1-line alpha) -------
__global__ __launch_bounds__(256) void row_gather(
        const int* __restrict__ csr, const int* __restrict__ rowstart,
        const int* __restrict__ rowend,
        const float* __restrict__ al, const float* __restrict__ arp,
        const _Float16* __restrict__ h, float* __restrict__ out, int n) {
    const int r    = (blockIdx.x * 256 + threadIdx.x) >> 6;
    const int lane = threadIdx.x & 63;
    if (r >= n) return;
    const int s = rowstart[r];
    const int e = rowend[r];
    const int sl = lane & 15;
    if (s >= e) {                       // empty row -> zeros
        if (lane < 16) {
            float4 z = make_float4(0.f, 0.f, 0.f, 0.f);
            *(float4*)&out[(size_t)r * 128 + sl * 8]     = z;
            *(float4*)&out[(size_t)r * 128 + sl * 8 + 4] = z;
        }
        return;
    }
    const int   head = sl >> 1;         // head for this lane's 8 cols
    const float al_l = (sl < 8) ? al[r * 8 + sl] : 0.f;
    float acc[8];
#pragma unroll
    for (int i = 0; i < 8; ++i) acc[i] = 0.f;
    float rs = 0.f;
#pragma unroll 2
    for (int j = s; j < e; j += 4) {
        const int  jj    = j + (lane >> 4);
        const bool valid = jj < e;
        const int  c     = csr[valid ? jj : s];
        float av = 0.f;
        if (sl < 8 && valid) {
            const float* ap = &arp[(size_t)c * 16];
            float a = al_l + ap[sl];
            a  = (a >= 0.f) ? a : 0.2f * a;
            av = __expf(a) * ap[8];     // pos shares the ar cache line
            rs += av;
        }
        const float alpha = __shfl(av, (lane & 48) + head, 64);
        float4 hv = *(const float4*)&h[(size_t)c * 128 + sl * 8];
        const __half2* hp = (const __half2*)&hv;
        const float2 f0 = __half22float2(hp[0]);
        const float2 f1 = __half22float2(hp[1]);
        const float2 f2 = __half22float2(hp[2]);
        const float2 f3 = __half22float2(hp[3]);
        acc[0] = fmaf(alpha, f0.x, acc[0]);
        acc[1] = fmaf(alpha, f0.y, acc[1]);
        acc[2] = fmaf(alpha, f1.x, acc[2]);
        acc[3] = fmaf(alpha, f1.y, acc[3]);
        acc[4] = fmaf(alpha, f2.x, acc[4]);
        acc[5] = fmaf(alpha, f2.y, acc[5]);
        acc[6] = fmaf(alpha, f3.x, acc[6]);
        acc[7] = fmaf(alpha, f3.y, acc[7]);
    }
    // merge the four 16-lane groups
    rs += __shfl_xor(rs, 16, 64);
    rs += __shfl_xor(rs, 32, 64);
#pragma unroll
    for (int i = 0; i < 8; ++i) {
        acc[i] += __shfl_xor(acc[i], 16, 64);
        acc[i] += __shfl_xor(acc[i], 32, 64);
    }
    const float rsh = __shfl(rs, (lane & 48) + head, 64); // rowsum for head
    const float sc  = (rsh != 0.f) ? (1.f / rsh + 1e-16f) : 0.f;
    if (lane < 16) {
        float4 o0 = make_float4(acc[0] * sc, acc[1] * sc, acc[2] * sc, acc[3] * sc);
        float4 o1 = make_float4(acc[4] * sc, acc[5] * sc, acc[6] * sc, acc[7] * sc);
        *(float4*)&out[(size_t)r * 128 + sl * 8]     = o0;
        *(float4*)&out[(size_t)r * 128 + sl * 8 + 4] = o1;
    }
}

extern "C" void kernel_launch(void* const* d_in, const int* in_sizes, int n_in,
                              void* d_out, int out_size, void* d_ws, size_t ws_size,
                              hipStream_t stream) {
    // identify inputs by unique sizes (robust to ordering)
    const float* x   = nullptr;
    const int*   ei  = nullptr;
    const float* pos = nullptr;
    const float* W   = nullptr;
    const float* att = nullptr;
    int E2 = 0;
    for (int i = 0; i < n_in; ++i) {
        int s = in_sizes[i];
        if      (s == out_size)        x   = (const float*)d_in[i];
        else if (s == out_size / 128)  pos = (const float*)d_in[i];
        else if (s == 16384)           W   = (const float*)d_in[i];
        else if (s == 256)             att = (const float*)d_in[i];
        else { ei = (const int*)d_in[i]; E2 = s; }
    }
    float* out = (float*)d_out;
    const int N_ = out_size / 128;     // 100000
    const int E_ = E2 / 2;             // 1600000
    const int NB = (N_ + BK - 1) / BK; // 196 buckets

    // workspace
    _Float16* h   = (_Float16*)d_ws;                  // N*128 halves (25.6 MB)
    float* al     = (float*)(h + (size_t)N_ * 128);   // N*8
    float* arp    = al + (size_t)N_ * 8;              // N*16 (ar[8],pos,pad)
    _Float16* WBh = (_Float16*)(arp + (size_t)N_ * 16);
    _Float16* WBl = WBh + 16384;
    int* rowstart = (int*)(WBl + 16384);
    int* rowend   = rowstart + N_;
    int* bbase    = rowend + N_;
    int* gcur     = bbase + NBMAX;
    int* csr      = gcur + NBMAX;
    int* bins     = csr + E_;                         // NB*BCAP ints (7.2 MB)

    hipMemsetAsync(gcur, 0, (size_t)NBMAX * sizeof(int), stream);

    prep_w<<<64, 256, 0, stream>>>(W, WBh, WBl);
    node_h<<<(N_ + 63) / 64, 256, 0, stream>>>(x, WBh, WBl, att, pos,
                                               h, al, arp, N_);
    bin_edges<<<(E_ + 256 * EPB - 1) / (256 * EPB), 256, 0, stream>>>(
        ei, gcur, bins, E_, NB);
    scan_top<<<1, 256, 0, stream>>>(gcur, bbase, NB);
    bucket_fill<<<NB, 512, 0, stream>>>(bins, gcur, bbase, rowstart, rowend,
                                        csr, N_);
    row_gather<<<(N_ * 64 + 255) / 256, 256, 0, stream>>>(
        csr, rowstart, rowend, al, arp, h, out, N_);
}

// Round 7
// 259.937 us; speedup vs baseline: 2.0676x; 1.0895x over previous
//
#include <hip/hip_runtime.h>
#include <hip/hip_fp16.h>

// ---------------------------------------------------------------------------
// Pipeline: prep_w (W,att -> MFMA-swizzled fp16 hi/lo tables; 9th coltile is
// fused AL/AR weights), node_h (pure-MFMA split-fp16 GEMM -> h fp16, al f32,
// arh fp16 -- no shuffle epilogue), bin_edges (512-thr LDS counting-sort),
// bucket_fill (fused base+count+scan+csr scatter, 391 blocks),
// row_gather (wave/row, 4 edges/iter; arh 1.6MB + pos 0.4MB L2-resident).
// ---------------------------------------------------------------------------

#define BK    256      // rows per bucket
#define BSH   8
#define NBMAX 512      // max buckets (N <= 131072)
#define BCAP  4736     // bin capacity per bucket (mean 4092, +10 sigma)
#define EPB   8        // edges per thread in bin_edges (4096 per block)

typedef _Float16 half8 __attribute__((ext_vector_type(8)));
typedef float    f32x4 __attribute__((ext_vector_type(4)));

// ---- W,att -> MFMA-B-swizzled fp16 hi/lo tables (9 coltiles) --------------
// index = ((ks*9 + ct)*64 + lane)*8 + j ; ct<8: W cols; ct==8: AL/AR fused.
__global__ __launch_bounds__(256) void prep_w(
        const float* __restrict__ W, const float* __restrict__ att,
        _Float16* __restrict__ WBh, _Float16* __restrict__ WBl) {
    int i = blockIdx.x * 256 + threadIdx.x;
    if (i >= 4 * 9 * 64 * 8) return;          // 18432
    const int j    = i & 7;
    const int lane = (i >> 3) & 63;
    const int ctks = i >> 9;                  // 0..35
    const int ct   = ctks % 9;
    const int ks   = ctks / 9;
    const int nn   = lane & 15;
    const int kg   = lane >> 4;
    const int k    = ks * 32 + kg * 8 + j;
    float w;
    if (ct < 8) {
        w = W[(ct * 16 + nn) * 128 + k];
    } else {                                  // fused attention weights
        const int head = nn & 7;
        const int sel  = nn >> 3;             // 0: AL, 1: AR
        float s = 0.f;
        for (int d = 0; d < 16; ++d)
            s += att[head * 32 + sel * 16 + d] * W[(head * 16 + d) * 128 + k];
        w = s;
    }
    const _Float16 hi = (_Float16)w;
    WBh[i] = hi;
    WBl[i] = (_Float16)(w - (float)hi);
}

// ---- h = x @ W^T via MFMA (split-fp16, fp32-grade); al/arh from coltile 8 -
// 64 nodes/block, 4 waves; wave computes 16 nodes x 144 cols (9 coltiles).
// A: row m = lane&15, k = kg*8+j. D: col = ct*16+m, node-in-16 = kg*4+r.
__global__ __launch_bounds__(256) void node_h(
        const float* __restrict__ x, const _Float16* __restrict__ WBh,
        const _Float16* __restrict__ WBl,
        _Float16* __restrict__ h, float* __restrict__ al,
        _Float16* __restrict__ arh, int n) {
    const int t    = threadIdx.x;
    const int wv   = t >> 6;
    const int lane = t & 63;
    const int m    = lane & 15;
    const int kg   = lane >> 4;
    const int nodeA = blockIdx.x * 64 + wv * 16 + m;
    const bool avalid = nodeA < n;

    f32x4 acc[9];
#pragma unroll
    for (int ct = 0; ct < 9; ++ct) acc[ct] = (f32x4)0.f;

    const half8* bh = (const half8*)WBh;
    const half8* bl = (const half8*)WBl;

#pragma unroll
    for (int ks = 0; ks < 4; ++ks) {
        float xv[8];
        if (avalid) {
            const float4* xp =
                (const float4*)&x[(size_t)nodeA * 128 + ks * 32 + kg * 8];
            *(float4*)&xv[0] = xp[0];
            *(float4*)&xv[4] = xp[1];
        } else {
#pragma unroll
            for (int j = 0; j < 8; ++j) xv[j] = 0.f;
        }
        half8 axh, axl;
#pragma unroll
        for (int j = 0; j < 8; ++j) {
            const _Float16 hi = (_Float16)xv[j];
            axh[j] = hi;
            axl[j] = (_Float16)(xv[j] - (float)hi);
        }
#pragma unroll
        for (int ct = 0; ct < 9; ++ct) {
            const half8 bhv = bh[(ks * 9 + ct) * 64 + lane];
            const half8 blv = bl[(ks * 9 + ct) * 64 + lane];
            acc[ct] = __builtin_amdgcn_mfma_f32_16x16x32_f16(axl, bhv, acc[ct], 0, 0, 0);
            acc[ct] = __builtin_amdgcn_mfma_f32_16x16x32_f16(axh, blv, acc[ct], 0, 0, 0);
            acc[ct] = __builtin_amdgcn_mfma_f32_16x16x32_f16(axh, bhv, acc[ct], 0, 0, 0);
        }
    }

    const int nodeD0 = blockIdx.x * 64 + wv * 16 + kg * 4;
#pragma unroll
    for (int r = 0; r < 4; ++r) {
        const int node = nodeD0 + r;
        if (node < n) {
            // h: col = ct*16 + m
#pragma unroll
            for (int ct = 0; ct < 8; ++ct)
                h[(size_t)node * 128 + ct * 16 + m] = (_Float16)acc[ct][r];
            // coltile 8: m<8 -> al[head=m] (f32); m>=8 -> arh[head=m-8] (fp16)
            if (m < 8) al[node * 8 + m] = acc[8][r];
            else       arh[node * 8 + (m - 8)] = (_Float16)acc[8][r];
        }
    }
}

// ---- bin pass: LDS counting-sort by bucket, coalesced bin writes ----------
// bucket = row >> 8; packed entry = c | (rlow << 17)  (c<2^17, rlow<2^8).
__global__ __launch_bounds__(512) void bin_edges(
        const int* __restrict__ ei, int* __restrict__ gcur,
        int* __restrict__ bins, int E, int nb) {
    __shared__ int  cnt[NBMAX];
    __shared__ int  basep[NBMAX];
    __shared__ int  lstart[NBMAX];
    __shared__ int2 sorted[512 * EPB];        // 32 KB
    const int t    = threadIdx.x;
    const int base = blockIdx.x * (512 * EPB);
    cnt[t] = 0;
    __syncthreads();

    int rr[EPB], off[EPB];
#pragma unroll
    for (int j = 0; j < EPB; ++j) {
        const int e = base + j * 512 + t;
        if (e < E) {
            rr[j]  = ei[e];
            off[j] = atomicAdd(&cnt[rr[j] >> BSH], 1);
        } else rr[j] = -1;
    }
    __syncthreads();
    // exclusive scan of cnt -> lstart; reserve global space -> basep
    const int v = cnt[t];
    lstart[t] = v;
    __syncthreads();
    for (int o = 1; o < 512; o <<= 1) {
        const int tmp = (t >= o) ? lstart[t - o] : 0;
        __syncthreads();
        lstart[t] += tmp;
        __syncthreads();
    }
    const int incl = lstart[t];
    __syncthreads();
    lstart[t] = incl - v;                     // exclusive
    basep[t]  = (t < nb && v > 0) ? atomicAdd(&gcur[t], v) : 0;
    __syncthreads();

    // place into LDS sorted by bucket
#pragma unroll
    for (int j = 0; j < EPB; ++j) {
        if (rr[j] >= 0) {
            const int e = base + j * 512 + t;
            const int b = rr[j] >> BSH;
            sorted[lstart[b] + off[j]] = make_int2(ei[E + e], rr[j]);
        }
    }
    __syncthreads();

    // coalesced write-out (runs per bucket are contiguous)
    const int total = lstart[511] + cnt[511];
    for (int i = t; i < total; i += 512) {
        const int2 p = sorted[i];
        const int  b = p.y >> BSH;
        const int  q = basep[b] + i - lstart[b];
        if (q < BCAP)
            bins[(size_t)b * BCAP + q] = p.x | ((p.y & (BK - 1)) << 17);
    }
}

// ---- fused per-bucket: base + degree count + scan + csr + rowstart/end ----
__global__ __launch_bounds__(256) void bucket_fill(
        const int* __restrict__ bins, const int* __restrict__ gcur,
        int* __restrict__ rowstart, int* __restrict__ rowend,
        int* __restrict__ csr, int n, int nb) {
    __shared__ int ld[BK], sc[BK], cur[BK];
    const int b = blockIdx.x, t = threadIdx.x;
    // bucket base = sum over b' < b of min(gcur[b'], BCAP)
    int pv = 0;
    for (int i = t; i < b; i += 256) pv += min(gcur[i], BCAP);
    sc[t] = pv;
    __syncthreads();
    for (int o = 128; o > 0; o >>= 1) {
        if (t < o) sc[t] += sc[t + o];
        __syncthreads();
    }
    const int bbase = sc[0];
    __syncthreads();
    ld[t] = 0;
    __syncthreads();
    const int cnt = min(gcur[b], BCAP);
    const int* bp = bins + (size_t)b * BCAP;
    for (int i = t; i < cnt; i += 256)
        atomicAdd(&ld[((unsigned)bp[i]) >> 17], 1);
    __syncthreads();
    const int v = ld[t];
    sc[t] = v;
    __syncthreads();
    for (int o = 1; o < 256; o <<= 1) {
        const int tmp = (t >= o) ? sc[t - o] : 0;
        __syncthreads();
        sc[t] += tmp;
        __syncthreads();
    }
    const int node = b * BK + t;
    const int s0   = sc[t] - v + bbase;
    cur[t] = s0;
    if (node < n) rowstart[node] = s0;
    __syncthreads();
    for (int i = t; i < cnt; i += 256) {
        const int vv = bp[i];
        const int q  = atomicAdd(&cur[((unsigned)vv) >> 17], 1);
        csr[q] = vv & 0x1FFFF;
    }
    __syncthreads();
    if (node < n) rowend[node] = cur[t];
}

// ---- wave per row, 4 edges/iter; arh (1.6MB) + pos (0.4MB) L2-resident ----
__global__ __launch_bounds__(256) void row_gather(
        const int* __restrict__ csr, const int* __restrict__ rowstart,
        const int* __restrict__ rowend,
        const float* __restrict__ al, const _Float16* __restrict__ arh,
        const float* __restrict__ pos, const _Float16* __restrict__ h,
        float* __restrict__ out, int n) {
    const int r    = (blockIdx.x * 256 + threadIdx.x) >> 6;
    const int lane = threadIdx.x & 63;
    if (r >= n) return;
    const int s = rowstart[r];
    const int e = rowend[r];
    const int sl = lane & 15;
    if (s >= e) {                       // empty row -> zeros
        if (lane < 16) {
            float4 z = make_float4(0.f, 0.f, 0.f, 0.f);
            *(float4*)&out[(size_t)r * 128 + sl * 8]     = z;
            *(float4*)&out[(size_t)r * 128 + sl * 8 + 4] = z;
        }
        return;
    }
    const int   head = sl >> 1;         // head for this lane's 8 cols
    const float al_l = (sl < 8) ? al[r * 8 + sl] : 0.f;
    float acc[8];
#pragma unroll
    for (int i = 0; i < 8; ++i) acc[i] = 0.f;
    float rs = 0.f;
#pragma unroll 2
    for (int j = s; j < e; j += 4) {
        const int  jj    = j + (lane >> 4);
        const bool valid = jj < e;
        const int  c     = csr[valid ? jj : s];
        float av = 0.f;
        if (sl < 8 && valid) {
            float a = al_l + (float)arh[(size_t)c * 8 + sl];
            a  = (a >= 0.f) ? a : 0.2f * a;
            av = __expf(a) * pos[c];
            rs += av;
        }
        const float alpha = __shfl(av, (lane & 48) + head, 64);
        float4 hv = *(const float4*)&h[(size_t)c * 128 + sl * 8];
        const __half2* hp = (const __half2*)&hv;
        const float2 f0 = __half22float2(hp[0]);
        const float2 f1 = __half22float2(hp[1]);
        const float2 f2 = __half22float2(hp[2]);
        const float2 f3 = __half22float2(hp[3]);
        acc[0] = fmaf(alpha, f0.x, acc[0]);
        acc[1] = fmaf(alpha, f0.y, acc[1]);
        acc[2] = fmaf(alpha, f1.x, acc[2]);
        acc[3] = fmaf(alpha, f1.y, acc[3]);
        acc[4] = fmaf(alpha, f2.x, acc[4]);
        acc[5] = fmaf(alpha, f2.y, acc[5]);
        acc[6] = fmaf(alpha, f3.x, acc[6]);
        acc[7] = fmaf(alpha, f3.y, acc[7]);
    }
    // merge the four 16-lane groups
    rs += __shfl_xor(rs, 16, 64);
    rs += __shfl_xor(rs, 32, 64);
#pragma unroll
    for (int i = 0; i < 8; ++i) {
        acc[i] += __shfl_xor(acc[i], 16, 64);
        acc[i] += __shfl_xor(acc[i], 32, 64);
    }
    const float rsh = __shfl(rs, (lane & 48) + head, 64); // rowsum for head
    const float sc  = (rsh != 0.f) ? (1.f / rsh + 1e-16f) : 0.f;
    if (lane < 16) {
        float4 o0 = make_float4(acc[0] * sc, acc[1] * sc, acc[2] * sc, acc[3] * sc);
        float4 o1 = make_float4(acc[4] * sc, acc[5] * sc, acc[6] * sc, acc[7] * sc);
        *(float4*)&out[(size_t)r * 128 + sl * 8]     = o0;
        *(float4*)&out[(size_t)r * 128 + sl * 8 + 4] = o1;
    }
}

extern "C" void kernel_launch(void* const* d_in, const int* in_sizes, int n_in,
                              void* d_out, int out_size, void* d_ws, size_t ws_size,
                              hipStream_t stream) {
    // identify inputs by unique sizes (robust to ordering)
    const float* x   = nullptr;
    const int*   ei  = nullptr;
    const float* pos = nullptr;
    const float* W   = nullptr;
    const float* att = nullptr;
    int E2 = 0;
    for (int i = 0; i < n_in; ++i) {
        int s = in_sizes[i];
        if      (s == out_size)        x   = (const float*)d_in[i];
        else if (s == out_size / 128)  pos = (const float*)d_in[i];
        else if (s == 16384)           W   = (const float*)d_in[i];
        else if (s == 256)             att = (const float*)d_in[i];
        else { ei = (const int*)d_in[i]; E2 = s; }
    }
    float* out = (float*)d_out;
    const int N_ = out_size / 128;     // 100000
    const int E_ = E2 / 2;             // 1600000
    const int NB = (N_ + BK - 1) / BK; // 391 buckets

    // workspace
    _Float16* h   = (_Float16*)d_ws;                  // N*128 fp16 (25.6 MB)
    float*    al  = (float*)(h + (size_t)N_ * 128);   // N*8 f32   (3.2 MB)
    _Float16* arh = (_Float16*)(al + (size_t)N_ * 8); // N*8 fp16  (1.6 MB)
    _Float16* WBh = arh + (size_t)N_ * 8;
    _Float16* WBl = WBh + 18432;
    int* rowstart = (int*)(WBl + 18432);
    int* rowend   = rowstart + N_;
    int* gcur     = rowend + N_;
    int* csr      = gcur + NBMAX;
    int* bins     = csr + E_;                         // NB*BCAP ints (7.4 MB)

    hipMemsetAsync(gcur, 0, (size_t)NBMAX * sizeof(int), stream);

    prep_w<<<72, 256, 0, stream>>>(W, att, WBh, WBl);
    node_h<<<(N_ + 63) / 64, 256, 0, stream>>>(x, WBh, WBl, h, al, arh, N_);
    bin_edges<<<(E_ + 512 * EPB - 1) / (512 * EPB), 512, 0, stream>>>(
        ei, gcur, bins, E_, NB);
    bucket_fill<<<NB, 256, 0, stream>>>(bins, gcur, rowstart, rowend,
                                        csr, N_, NB);
    row_gather<<<(N_ * 64 + 255) / 256, 256, 0, stream>>>(
        csr, rowstart, rowend, al, arh, pos, h, out, N_);
}

// Round 8
// 252.054 us; speedup vs baseline: 2.1323x; 1.0313x over previous
//
#include <hip/hip_runtime.h>
#include <hip/hip_fp16.h>

// ---------------------------------------------------------------------------
// Pipeline: prep_w (W,att -> MFMA-swizzled fp16 hi/lo tables; 9th coltile is
// fused AL/AR weights), node_h (pure-MFMA split-fp16 GEMM -> h fp16, al f32,
// arh fp16), bin_edges (512-thr LDS counting-sort), bucket_fill (single
// global read, LDS-staged count+scan+csr scatter, rowse int2),
// row_gather (wave/row, 8 edges/iter: 64-lane alpha phase (8 edges x 8 heads)
// + two 4-edge FMA substeps -> 2x memory-level parallelism).
// ---------------------------------------------------------------------------

#define BK    256      // rows per bucket
#define BSH   8
#define NBMAX 512      // max buckets (N <= 131072)
#define BCAP  4736     // bin capacity per bucket (mean 4092, +10 sigma)
#define EPB   8        // edges per thread in bin_edges (4096 per block)

typedef _Float16 half8 __attribute__((ext_vector_type(8)));
typedef float    f32x4 __attribute__((ext_vector_type(4)));

// ---- W,att -> MFMA-B-swizzled fp16 hi/lo tables (9 coltiles) --------------
// index = ((ks*9 + ct)*64 + lane)*8 + j ; ct<8: W cols; ct==8: AL/AR fused.
__global__ __launch_bounds__(256) void prep_w(
        const float* __restrict__ W, const float* __restrict__ att,
        _Float16* __restrict__ WBh, _Float16* __restrict__ WBl) {
    int i = blockIdx.x * 256 + threadIdx.x;
    if (i >= 4 * 9 * 64 * 8) return;          // 18432
    const int j    = i & 7;
    const int lane = (i >> 3) & 63;
    const int ctks = i >> 9;                  // 0..35
    const int ct   = ctks % 9;
    const int ks   = ctks / 9;
    const int nn   = lane & 15;
    const int kg   = lane >> 4;
    const int k    = ks * 32 + kg * 8 + j;
    float w;
    if (ct < 8) {
        w = W[(ct * 16 + nn) * 128 + k];
    } else {                                  // fused attention weights
        const int head = nn & 7;
        const int sel  = nn >> 3;             // 0: AL, 1: AR
        float s = 0.f;
        for (int d = 0; d < 16; ++d)
            s += att[head * 32 + sel * 16 + d] * W[(head * 16 + d) * 128 + k];
        w = s;
    }
    const _Float16 hi = (_Float16)w;
    WBh[i] = hi;
    WBl[i] = (_Float16)(w - (float)hi);
}

// ---- h = x @ W^T via MFMA (split-fp16, fp32-grade); al/arh from coltile 8 -
__global__ __launch_bounds__(256) void node_h(
        const float* __restrict__ x, const _Float16* __restrict__ WBh,
        const _Float16* __restrict__ WBl,
        _Float16* __restrict__ h, float* __restrict__ al,
        _Float16* __restrict__ arh, int n) {
    const int t    = threadIdx.x;
    const int wv   = t >> 6;
    const int lane = t & 63;
    const int m    = lane & 15;
    const int kg   = lane >> 4;
    const int nodeA = blockIdx.x * 64 + wv * 16 + m;
    const bool avalid = nodeA < n;

    f32x4 acc[9];
#pragma unroll
    for (int ct = 0; ct < 9; ++ct) acc[ct] = (f32x4)0.f;

    const half8* bh = (const half8*)WBh;
    const half8* bl = (const half8*)WBl;

#pragma unroll
    for (int ks = 0; ks < 4; ++ks) {
        float xv[8];
        if (avalid) {
            const float4* xp =
                (const float4*)&x[(size_t)nodeA * 128 + ks * 32 + kg * 8];
            *(float4*)&xv[0] = xp[0];
            *(float4*)&xv[4] = xp[1];
        } else {
#pragma unroll
            for (int j = 0; j < 8; ++j) xv[j] = 0.f;
        }
        half8 axh, axl;
#pragma unroll
        for (int j = 0; j < 8; ++j) {
            const _Float16 hi = (_Float16)xv[j];
            axh[j] = hi;
            axl[j] = (_Float16)(xv[j] - (float)hi);
        }
#pragma unroll
        for (int ct = 0; ct < 9; ++ct) {
            const half8 bhv = bh[(ks * 9 + ct) * 64 + lane];
            const half8 blv = bl[(ks * 9 + ct) * 64 + lane];
            acc[ct] = __builtin_amdgcn_mfma_f32_16x16x32_f16(axl, bhv, acc[ct], 0, 0, 0);
            acc[ct] = __builtin_amdgcn_mfma_f32_16x16x32_f16(axh, blv, acc[ct], 0, 0, 0);
            acc[ct] = __builtin_amdgcn_mfma_f32_16x16x32_f16(axh, bhv, acc[ct], 0, 0, 0);
        }
    }

    const int nodeD0 = blockIdx.x * 64 + wv * 16 + kg * 4;
#pragma unroll
    for (int r = 0; r < 4; ++r) {
        const int node = nodeD0 + r;
        if (node < n) {
#pragma unroll
            for (int ct = 0; ct < 8; ++ct)
                h[(size_t)node * 128 + ct * 16 + m] = (_Float16)acc[ct][r];
            if (m < 8) al[node * 8 + m] = acc[8][r];
            else       arh[node * 8 + (m - 8)] = (_Float16)acc[8][r];
        }
    }
}

// ---- bin pass: LDS counting-sort by bucket, coalesced bin writes ----------
__global__ __launch_bounds__(512) void bin_edges(
        const int* __restrict__ ei, int* __restrict__ gcur,
        int* __restrict__ bins, int E, int nb) {
    __shared__ int  cnt[NBMAX];
    __shared__ int  basep[NBMAX];
    __shared__ int  lstart[NBMAX];
    __shared__ int2 sorted[512 * EPB];        // 32 KB
    const int t    = threadIdx.x;
    const int base = blockIdx.x * (512 * EPB);
    cnt[t] = 0;
    __syncthreads();

    int rr[EPB], off[EPB];
#pragma unroll
    for (int j = 0; j < EPB; ++j) {
        const int e = base + j * 512 + t;
        if (e < E) {
            rr[j]  = ei[e];
            off[j] = atomicAdd(&cnt[rr[j] >> BSH], 1);
        } else rr[j] = -1;
    }
    __syncthreads();
    const int v = cnt[t];
    lstart[t] = v;
    __syncthreads();
    for (int o = 1; o < 512; o <<= 1) {
        const int tmp = (t >= o) ? lstart[t - o] : 0;
        __syncthreads();
        lstart[t] += tmp;
        __syncthreads();
    }
    const int incl = lstart[t];
    __syncthreads();
    lstart[t] = incl - v;                     // exclusive
    basep[t]  = (t < nb && v > 0) ? atomicAdd(&gcur[t], v) : 0;
    __syncthreads();

#pragma unroll
    for (int j = 0; j < EPB; ++j) {
        if (rr[j] >= 0) {
            const int e = base + j * 512 + t;
            const int b = rr[j] >> BSH;
            sorted[lstart[b] + off[j]] = make_int2(ei[E + e], rr[j]);
        }
    }
    __syncthreads();

    const int total = lstart[511] + cnt[511];
    for (int i = t; i < total; i += 512) {
        const int2 p = sorted[i];
        const int  b = p.y >> BSH;
        const int  q = basep[b] + i - lstart[b];
        if (q < BCAP)
            bins[(size_t)b * BCAP + q] = p.x | ((p.y & (BK - 1)) << 17);
    }
}

// ---- fused per-bucket: base + count + scan + csr scatter (1 global read) --
__global__ __launch_bounds__(256) void bucket_fill(
        const int* __restrict__ bins, const int* __restrict__ gcur,
        int2* __restrict__ rowse, int* __restrict__ csr, int n, int nb) {
    __shared__ int sh[BCAP];                  // 18.5 KB staged bin
    __shared__ int ld[BK], sc[BK], cur[BK];
    const int b = blockIdx.x, t = threadIdx.x;
    // bucket base = sum over b' < b of min(gcur[b'], BCAP)
    int pv = 0;
    for (int i = t; i < b; i += 256) pv += min(gcur[i], BCAP);
    sc[t] = pv;
    __syncthreads();
    for (int o = 128; o > 0; o >>= 1) {
        if (t < o) sc[t] += sc[t + o];
        __syncthreads();
    }
    const int bbase = sc[0];
    __syncthreads();
    ld[t] = 0;
    __syncthreads();
    const int cnt = min(gcur[b], BCAP);
    const int* bp = bins + (size_t)b * BCAP;
    for (int i = t; i < cnt; i += 256) {
        const int v = bp[i];
        sh[i] = v;
        atomicAdd(&ld[((unsigned)v) >> 17], 1);
    }
    __syncthreads();
    const int v = ld[t];
    sc[t] = v;
    __syncthreads();
    for (int o = 1; o < 256; o <<= 1) {
        const int tmp = (t >= o) ? sc[t - o] : 0;
        __syncthreads();
        sc[t] += tmp;
        __syncthreads();
    }
    const int node = b * BK + t;
    const int s0   = sc[t] - v + bbase;
    cur[t] = s0;
    __syncthreads();
    for (int i = t; i < cnt; i += 256) {
        const int vv = sh[i];
        const int q  = atomicAdd(&cur[((unsigned)vv) >> 17], 1);
        csr[q] = vv & 0x1FFFF;
    }
    __syncthreads();
    if (node < n) rowse[node] = make_int2(s0, cur[t]);
}

// ---- wave per row, 8 edges/iter (alpha: 8 edges x 8 heads on 64 lanes) ----
__global__ __launch_bounds__(256) void row_gather(
        const int* __restrict__ csr, const int2* __restrict__ rowse,
        const float* __restrict__ al, const _Float16* __restrict__ arh,
        const float* __restrict__ pos, const _Float16* __restrict__ h,
        float* __restrict__ out, int n) {
    const int r    = (blockIdx.x * 256 + threadIdx.x) >> 6;
    const int lane = threadIdx.x & 63;
    if (r >= n) return;
    const int2 se = rowse[r];
    const int s = se.x, e = se.y;
    const int sl = lane & 15;
    if (s >= e) {                       // empty row -> zeros
        if (lane < 16) {
            float4 z = make_float4(0.f, 0.f, 0.f, 0.f);
            *(float4*)&out[(size_t)r * 128 + sl * 8]     = z;
            *(float4*)&out[(size_t)r * 128 + sl * 8 + 4] = z;
        }
        return;
    }
    const int hd  = lane & 7;           // alpha phase: head
    const int es  = lane >> 3;          // alpha phase: edge slot 0..7
    const int esA = lane >> 4;          // FMA substeps: edge group 0..3
    const float al_h = al[r * 8 + hd];
    float acc[8];
#pragma unroll
    for (int i = 0; i < 8; ++i) acc[i] = 0.f;
    float rs = 0.f;
    for (int j = s; j < e; j += 8) {
        // phase 1: alpha for 8 edges x 8 heads (all 64 lanes distinct)
        const int  j1 = j + es;
        const bool v1 = j1 < e;
        const int  c1 = csr[v1 ? j1 : s];
        float av = 0.f;
        if (v1) {
            float a = al_h + (float)arh[(size_t)c1 * 8 + hd];
            a  = (a >= 0.f) ? a : 0.2f * a;
            av = __expf(a) * pos[c1];
            rs += av;
        }
        // substep A: edges j..j+3, 16 lanes each
        {
            const int  jA = j + esA;
            const int  cA = csr[(jA < e) ? jA : s];
            const float alpha = __shfl(av, esA * 8 + (sl >> 1), 64);
            float4 hv = *(const float4*)&h[(size_t)cA * 128 + sl * 8];
            const __half2* hp = (const __half2*)&hv;
            const float2 f0 = __half22float2(hp[0]);
            const float2 f1 = __half22float2(hp[1]);
            const float2 f2 = __half22float2(hp[2]);
            const float2 f3 = __half22float2(hp[3]);
            acc[0] = fmaf(alpha, f0.x, acc[0]);
            acc[1] = fmaf(alpha, f0.y, acc[1]);
            acc[2] = fmaf(alpha, f1.x, acc[2]);
            acc[3] = fmaf(alpha, f1.y, acc[3]);
            acc[4] = fmaf(alpha, f2.x, acc[4]);
            acc[5] = fmaf(alpha, f2.y, acc[5]);
            acc[6] = fmaf(alpha, f3.x, acc[6]);
            acc[7] = fmaf(alpha, f3.y, acc[7]);
        }
        // substep B: edges j+4..j+7
        {
            const int  jB = j + 4 + esA;
            const int  cB = csr[(jB < e) ? jB : s];
            const float alpha = __shfl(av, 32 + esA * 8 + (sl >> 1), 64);
            float4 hv = *(const float4*)&h[(size_t)cB * 128 + sl * 8];
            const __half2* hp = (const __half2*)&hv;
            const float2 f0 = __half22float2(hp[0]);
            const float2 f1 = __half22float2(hp[1]);
            const float2 f2 = __half22float2(hp[2]);
            const float2 f3 = __half22float2(hp[3]);
            acc[0] = fmaf(alpha, f0.x, acc[0]);
            acc[1] = fmaf(alpha, f0.y, acc[1]);
            acc[2] = fmaf(alpha, f1.x, acc[2]);
            acc[3] = fmaf(alpha, f1.y, acc[3]);
            acc[4] = fmaf(alpha, f2.x, acc[4]);
            acc[5] = fmaf(alpha, f2.y, acc[5]);
            acc[6] = fmaf(alpha, f3.x, acc[6]);
            acc[7] = fmaf(alpha, f3.y, acc[7]);
        }
    }
    // rs: merge the 8 edge slots (lanes with equal (lane&7) hold same head)
    rs += __shfl_xor(rs, 8, 64);
    rs += __shfl_xor(rs, 16, 64);
    rs += __shfl_xor(rs, 32, 64);
    // acc: merge the four 16-lane groups
#pragma unroll
    for (int i = 0; i < 8; ++i) {
        acc[i] += __shfl_xor(acc[i], 16, 64);
        acc[i] += __shfl_xor(acc[i], 32, 64);
    }
    const float rsh = __shfl(rs, (lane & 15) >> 1, 64); // rowsum for head sl>>1
    const float sc  = (rsh != 0.f) ? (1.f / rsh + 1e-16f) : 0.f;
    if (lane < 16) {
        float4 o0 = make_float4(acc[0] * sc, acc[1] * sc, acc[2] * sc, acc[3] * sc);
        float4 o1 = make_float4(acc[4] * sc, acc[5] * sc, acc[6] * sc, acc[7] * sc);
        *(float4*)&out[(size_t)r * 128 + sl * 8]     = o0;
        *(float4*)&out[(size_t)r * 128 + sl * 8 + 4] = o1;
    }
}

extern "C" void kernel_launch(void* const* d_in, const int* in_sizes, int n_in,
                              void* d_out, int out_size, void* d_ws, size_t ws_size,
                              hipStream_t stream) {
    // identify inputs by unique sizes (robust to ordering)
    const float* x   = nullptr;
    const int*   ei  = nullptr;
    const float* pos = nullptr;
    const float* W   = nullptr;
    const float* att = nullptr;
    int E2 = 0;
    for (int i = 0; i < n_in; ++i) {
        int s = in_sizes[i];
        if      (s == out_size)        x   = (const float*)d_in[i];
        else if (s == out_size / 128)  pos = (const float*)d_in[i];
        else if (s == 16384)           W   = (const float*)d_in[i];
        else if (s == 256)             att = (const float*)d_in[i];
        else { ei = (const int*)d_in[i]; E2 = s; }
    }
    float* out = (float*)d_out;
    const int N_ = out_size / 128;     // 100000
    const int E_ = E2 / 2;             // 1600000
    const int NB = (N_ + BK - 1) / BK; // 391 buckets

    // workspace
    _Float16* h   = (_Float16*)d_ws;                  // N*128 fp16 (25.6 MB)
    float*    al  = (float*)(h + (size_t)N_ * 128);   // N*8 f32   (3.2 MB)
    _Float16* arh = (_Float16*)(al + (size_t)N_ * 8); // N*8 fp16  (1.6 MB)
    _Float16* WBh = arh + (size_t)N_ * 8;
    _Float16* WBl = WBh + 18432;
    int2* rowse   = (int2*)(WBl + 18432);             // N int2
    int* gcur     = (int*)(rowse + N_);
    int* csr      = gcur + NBMAX;
    int* bins     = csr + E_;                         // NB*BCAP ints (7.4 MB)

    hipMemsetAsync(gcur, 0, (size_t)NBMAX * sizeof(int), stream);

    prep_w<<<72, 256, 0, stream>>>(W, att, WBh, WBl);
    node_h<<<(N_ + 63) / 64, 256, 0, stream>>>(x, WBh, WBl, h, al, arh, N_);
    bin_edges<<<(E_ + 512 * EPB - 1) / (512 * EPB), 512, 0, stream>>>(
        ei, gcur, bins, E_, NB);
    bucket_fill<<<NB, 256, 0, stream>>>(bins, gcur, rowse, csr, N_, NB);
    row_gather<<<(N_ * 64 + 255) / 256, 256, 0, stream>>>(
        csr, rowse, al, arh, pos, h, out, N_);
}